// Round 1
// baseline (1511.466 us; speedup 1.0000x reference)
//
#include <hip/hip_runtime.h>
#include <hip/hip_bf16.h>

#define NNODES 50000
#define NEDGES 500000
#define DIM    384
#define NB     64
#define SLOPE  0.2f
#define LN_EPS 1e-5f
#define EPRIME (NEDGES + NNODES)

// ---------- helpers ----------
__device__ __forceinline__ unsigned f2ord(float f) {
  unsigned u = __float_as_uint(f);
  return (u & 0x80000000u) ? ~u : (u | 0x80000000u);
}
__device__ __forceinline__ float ord2f(unsigned k) {
  return (k & 0x80000000u) ? __uint_as_float(k & 0x7fffffffu) : __uint_as_float(~k);
}
// flag: 1 -> buffer holds int64, 0 -> int32
__device__ __forceinline__ int load_i(const void* p, long long i, int is64) {
  return is64 ? (int)((const long long*)p)[i] : ((const int*)p)[i];
}

// ---------- dtype detect (int64 vs int32) ----------
// If int64: odd int32 positions (high words) of first 256 entries are all 0.
__global__ void detect_kernel(const int* __restrict__ ei32, int* __restrict__ flag) {
  __shared__ int nz;
  if (threadIdx.x == 0) nz = 0;
  __syncthreads();
  if (ei32[2 * threadIdx.x + 1] != 0) atomicAdd(&nz, 1);
  __syncthreads();
  if (threadIdx.x == 0) *flag = (nz == 0) ? 1 : 0;
}

// ---------- CSR build ----------
__global__ void count_kernel(const void* __restrict__ ei, const int* __restrict__ flag,
                             int* __restrict__ deg) {
  int is64 = *flag;
  for (int i = blockIdx.x * blockDim.x + threadIdx.x; i < EPRIME; i += gridDim.x * blockDim.x) {
    int d = (i < NEDGES) ? load_i(ei, (long long)NEDGES + i, is64) : (i - NEDGES);
    atomicAdd(&deg[d], 1);
  }
}

__global__ void scan_kernel(const int* __restrict__ deg, int* __restrict__ row_ptr,
                            int* __restrict__ cursor) {
  __shared__ int buf[1024];
  __shared__ int carry;
  int t = threadIdx.x;
  if (t == 0) carry = 0;
  __syncthreads();
  for (int base = 0; base < NNODES; base += 1024) {
    int idx = base + t;
    int v = (idx < NNODES) ? deg[idx] : 0;
    buf[t] = v;
    __syncthreads();
    for (int off = 1; off < 1024; off <<= 1) {
      int x = (t >= off) ? buf[t - off] : 0;
      __syncthreads();
      buf[t] += x;
      __syncthreads();
    }
    int excl = carry + buf[t] - v;
    if (idx < NNODES) { row_ptr[idx] = excl; cursor[idx] = excl; }
    __syncthreads();
    if (t == 0) carry += buf[1023];
    __syncthreads();
  }
  if (t == 0) row_ptr[NNODES] = carry;
}

__global__ void scatter_kernel(const void* __restrict__ ei, const int* __restrict__ flag,
                               int* __restrict__ cursor, int* __restrict__ srt) {
  int is64 = *flag;
  for (int i = blockIdx.x * blockDim.x + threadIdx.x; i < EPRIME; i += gridDim.x * blockDim.x) {
    int s, d;
    if (i < NEDGES) { s = load_i(ei, i, is64); d = load_i(ei, (long long)NEDGES + i, is64); }
    else            { s = d = i - NEDGES; }
    int pos = atomicAdd(&cursor[d], 1);
    srt[pos] = s;
  }
}

// ---------- f32 GEMM: C[M,384] = A[M,384] @ B[384,384] ----------
__global__ __launch_bounds__(256)
void gemm_kernel(const float* __restrict__ A, const float* __restrict__ B,
                 float* __restrict__ Cmat) {
  __shared__ float As[16][68];   // transposed: As[k][m], +4 pad keeps 16B align
  __shared__ float Bs[16][64];
  int bm = blockIdx.x * 64;
  int bn = blockIdx.y * 64;
  int tid = threadIdx.x;
  int arow = tid >> 2, akq = (tid & 3) << 2;
  int bkr = tid >> 4, bnq = (tid & 15) << 2;
  int trow = (tid >> 4) << 2, tcol = (tid & 15) << 2;
  int ar = bm + arow; if (ar >= NNODES) ar = NNODES - 1;   // clamp: OOB rows feed only discarded accs
  const float* Aptr = A + (size_t)ar * DIM + akq;
  const float* Bptr = B + (size_t)bkr * DIM + bn + bnq;
  float acc[4][4] = {};
  for (int k0 = 0; k0 < DIM; k0 += 16) {
    float4 av = *(const float4*)(Aptr + k0);
    float4 bv = *(const float4*)(Bptr + (size_t)k0 * DIM);
    __syncthreads();
    As[akq + 0][arow] = av.x; As[akq + 1][arow] = av.y;
    As[akq + 2][arow] = av.z; As[akq + 3][arow] = av.w;
    *(float4*)&Bs[bkr][bnq] = bv;
    __syncthreads();
#pragma unroll
    for (int k = 0; k < 16; ++k) {
      float4 a4 = *(const float4*)&As[k][trow];
      float4 b4 = *(const float4*)&Bs[k][tcol];
      float aa[4] = {a4.x, a4.y, a4.z, a4.w};
      float bb[4] = {b4.x, b4.y, b4.z, b4.w};
#pragma unroll
      for (int i = 0; i < 4; ++i)
#pragma unroll
        for (int j = 0; j < 4; ++j)
          acc[i][j] = fmaf(aa[i], bb[j], acc[i][j]);
    }
  }
#pragma unroll
  for (int i = 0; i < 4; ++i) {
    int r = bm + trow + i;
    if (r < NNODES) {
      float4 o = make_float4(acc[i][0], acc[i][1], acc[i][2], acc[i][3]);
      *(float4*)(Cmat + (size_t)r * DIM + bn + tcol) = o;
    }
  }
}

// ---------- attention scores: s[n,h] = sum_c h[n,h,c] * a[h,c] ----------
template <int H>
__global__ void score_kernel(const float* __restrict__ hmat,
                             const float* __restrict__ asrc, const float* __restrict__ adst,
                             float* __restrict__ ssrc, float* __restrict__ sdst) {
  constexpr int C = DIM / H;
  constexpr int PER = C / 32;
  int n = blockIdx.x;
  int t = threadIdx.x;               // H*32 threads
  int hh = t >> 5, lane = t & 31;
  const float* row = hmat + (size_t)n * DIM + hh * C;
  const float* as = asrc + hh * C;
  const float* ad = adst + hh * C;
  float s1 = 0.f, s2 = 0.f;
#pragma unroll
  for (int i = 0; i < PER; ++i) {
    float v = row[i * 32 + lane];
    s1 += v * as[i * 32 + lane];
    s2 += v * ad[i * 32 + lane];
  }
#pragma unroll
  for (int off = 16; off > 0; off >>= 1) {
    s1 += __shfl_down(s1, off, 32);
    s2 += __shfl_down(s2, off, 32);
  }
  if (lane == 0) { ssrc[n * H + hh] = s1; sdst[n * H + hh] = s2; }
}

// ---------- per-dst-node softmax + aggregation + fused epilogue ----------
// MODE 0: out = relu(LN(agg + bias)*g + be)   -> outbuf = next-layer features
// MODE 1: out = relu(agg + bias) + xres       -> outbuf = residual features (pre-pool)
template <int H, int MODE>
__global__ __launch_bounds__(128)
void aggregate_kernel(const int* __restrict__ row_ptr, const int* __restrict__ srt,
                      const float* __restrict__ ssrc, const float* __restrict__ sdst,
                      const float* __restrict__ hmat, const float* __restrict__ bias,
                      const float* __restrict__ gamma, const float* __restrict__ beta,
                      const float* __restrict__ xres, float* __restrict__ outbuf) {
  constexpr int C = DIM / H;
  constexpr int CH = 32;
  int n = blockIdx.x;
  int t = threadIdx.x;
  int start = row_ptr[n];
  int deg = row_ptr[n + 1] - start;

  __shared__ unsigned smax[H];
  __shared__ float sden[H], sdn[H], maxv[H], invd[H];
  __shared__ int lsrc[CH];
  __shared__ float lalpha[CH * H];
  __shared__ float red[256];

  if (t < H) { smax[t] = 0u; sden[t] = 0.f; sdn[t] = sdst[n * H + t]; }
  __syncthreads();
  // pass 1: per-head max of leaky_relu scores
  for (int i = t; i < deg * H; i += 128) {
    int e = i / H, hh = i - e * H;
    int s = srt[start + e];
    float v = ssrc[s * H + hh] + sdn[hh];
    v = (v > 0.f) ? v : SLOPE * v;
    atomicMax(&smax[hh], f2ord(v));
  }
  __syncthreads();
  if (t < H) maxv[t] = ord2f(smax[t]);
  __syncthreads();
  // pass 2: denom
  for (int i = t; i < deg * H; i += 128) {
    int e = i / H, hh = i - e * H;
    int s = srt[start + e];
    float v = ssrc[s * H + hh] + sdn[hh];
    v = (v > 0.f) ? v : SLOPE * v;
    atomicAdd(&sden[hh], __expf(v - maxv[hh]));
  }
  __syncthreads();
  if (t < H) invd[t] = 1.f / (sden[t] + 1e-16f);
  __syncthreads();

  // pass 3: chunked weighted accumulation; thread t owns columns t, t+128, t+256
  int j0 = t, j1 = t + 128, j2 = t + 256;
  int h0 = j0 / C, h1 = j1 / C, h2 = j2 / C;
  float a0 = 0.f, a1 = 0.f, a2 = 0.f;
  for (int base = 0; base < deg; base += CH) {
    int cnt = min(CH, deg - base);
    for (int i = t; i < cnt * H; i += 128) {
      int e = i / H, hh = i - e * H;
      int s = srt[start + base + e];
      if (hh == 0) lsrc[e] = s;
      float v = ssrc[s * H + hh] + sdn[hh];
      v = (v > 0.f) ? v : SLOPE * v;
      lalpha[e * H + hh] = __expf(v - maxv[hh]) * invd[hh];
    }
    __syncthreads();
    for (int e = 0; e < cnt; ++e) {
      const float* hr = hmat + (size_t)lsrc[e] * DIM;
      a0 = fmaf(lalpha[e * H + h0], hr[j0], a0);
      a1 = fmaf(lalpha[e * H + h1], hr[j1], a1);
      a2 = fmaf(lalpha[e * H + h2], hr[j2], a2);
    }
    __syncthreads();
  }
  float v0 = a0 + bias[j0], v1 = a1 + bias[j1], v2 = a2 + bias[j2];
  if (MODE == 0) {
    red[t] = v0 + v1 + v2;
    red[t + 128] = v0 * v0 + v1 * v1 + v2 * v2;
    __syncthreads();
    for (int off = 64; off > 0; off >>= 1) {
      if (t < off) { red[t] += red[t + off]; red[t + 128] += red[t + 128 + off]; }
      __syncthreads();
    }
    float mu = red[0] * (1.f / DIM);
    float var = red[128] * (1.f / DIM) - mu * mu;
    float rs = rsqrtf(var + LN_EPS);
    float y0 = (v0 - mu) * rs * gamma[j0] + beta[j0];
    float y1 = (v1 - mu) * rs * gamma[j1] + beta[j1];
    float y2 = (v2 - mu) * rs * gamma[j2] + beta[j2];
    size_t o = (size_t)n * DIM;
    outbuf[o + j0] = fmaxf(y0, 0.f);
    outbuf[o + j1] = fmaxf(y1, 0.f);
    outbuf[o + j2] = fmaxf(y2, 0.f);
  } else {
    size_t o = (size_t)n * DIM;
    outbuf[o + j0] = fmaxf(v0, 0.f) + xres[o + j0];
    outbuf[o + j1] = fmaxf(v1, 0.f) + xres[o + j1];
    outbuf[o + j2] = fmaxf(v2, 0.f) + xres[o + j2];
  }
}

// ---------- global mean pool (batch is sorted -> contiguous segments) ----------
__global__ void pool_kernel(const float* __restrict__ xr, const void* __restrict__ batch,
                            const int* __restrict__ flag, float* __restrict__ out) {
  int b = blockIdx.x;          // 64 graphs
  int t = threadIdx.x;         // 384 columns
  int is64 = *flag;
  int lo, hi;
  { int l = 0, r = NNODES;
    while (l < r) { int m = (l + r) >> 1; if (load_i(batch, m, is64) < b) l = m + 1; else r = m; }
    lo = l; }
  { int l = lo, r = NNODES;
    while (l < r) { int m = (l + r) >> 1; if (load_i(batch, m, is64) < b + 1) l = m + 1; else r = m; }
    hi = l; }
  float acc = 0.f;
  for (int n = lo; n < hi; ++n) acc += xr[(size_t)n * DIM + t];
  out[b * DIM + t] = acc / (float)max(hi - lo, 1);
}

// ---------- launch ----------
extern "C" void kernel_launch(void* const* d_in, const int* in_sizes, int n_in,
                              void* d_out, int out_size, void* d_ws, size_t ws_size,
                              hipStream_t stream) {
  const float* x    = (const float*)d_in[0];
  const void*  ei   = d_in[1];
  const void*  batch= d_in[2];
  const float* W1   = (const float*)d_in[3];
  const float* a1s  = (const float*)d_in[4];
  const float* a1d  = (const float*)d_in[5];
  const float* b1   = (const float*)d_in[6];
  const float* g1   = (const float*)d_in[7];
  const float* be1  = (const float*)d_in[8];
  const float* W2   = (const float*)d_in[9];
  const float* a2s  = (const float*)d_in[10];
  const float* a2d  = (const float*)d_in[11];
  const float* b2   = (const float*)d_in[12];
  const float* g2   = (const float*)d_in[13];
  const float* be2  = (const float*)d_in[14];
  const float* W3   = (const float*)d_in[15];
  const float* a3s  = (const float*)d_in[16];
  const float* a3d  = (const float*)d_in[17];
  const float* b3   = (const float*)d_in[18];
  float* out = (float*)d_out;

  char* ws = (char*)d_ws;
  size_t off = 0;
  auto alloc = [&](size_t bytes) -> void* {
    void* p = ws + off;
    off = (off + bytes + 255) & ~(size_t)255;
    return p;
  };
  int*   flag    = (int*)alloc(4);
  float* P       = (float*)alloc((size_t)NNODES * DIM * 4);   // h buffer
  float* Q       = (float*)alloc((size_t)NNODES * DIM * 4);   // feature ping-pong
  float* ssrc    = (float*)alloc((size_t)NNODES * 6 * 4);
  float* sdst    = (float*)alloc((size_t)NNODES * 6 * 4);
  int*   row_ptr = (int*)alloc((size_t)(NNODES + 1) * 4);
  int*   cursor  = (int*)alloc((size_t)NNODES * 4);
  int*   deg     = (int*)alloc((size_t)NNODES * 4);
  int*   srt     = (int*)alloc((size_t)EPRIME * 4);

  // CSR build (edges grouped by dst; self-loops appended implicitly)
  detect_kernel<<<1, 256, 0, stream>>>((const int*)ei, flag);
  hipMemsetAsync(deg, 0, (size_t)NNODES * 4, stream);
  int eblocks = (EPRIME + 255) / 256;
  count_kernel<<<eblocks, 256, 0, stream>>>(ei, flag, deg);
  scan_kernel<<<1, 1024, 0, stream>>>(deg, row_ptr, cursor);
  scatter_kernel<<<eblocks, 256, 0, stream>>>(ei, flag, cursor, srt);

  dim3 ggrid((NNODES + 63) / 64, DIM / 64);

  // layer 1: x -> Q
  gemm_kernel<<<ggrid, 256, 0, stream>>>(x, W1, P);
  score_kernel<4><<<NNODES, 128, 0, stream>>>(P, a1s, a1d, ssrc, sdst);
  aggregate_kernel<4, 0><<<NNODES, 128, 0, stream>>>(row_ptr, srt, ssrc, sdst, P, b1, g1, be1,
                                                     nullptr, Q);
  // layer 2: Q -> Q
  gemm_kernel<<<ggrid, 256, 0, stream>>>(Q, W2, P);
  score_kernel<4><<<NNODES, 128, 0, stream>>>(P, a2s, a2d, ssrc, sdst);
  aggregate_kernel<4, 0><<<NNODES, 128, 0, stream>>>(row_ptr, srt, ssrc, sdst, P, b2, g2, be2,
                                                     nullptr, Q);
  // layer 3: Q -> Q (residual with original x fused)
  gemm_kernel<<<ggrid, 256, 0, stream>>>(Q, W3, P);
  score_kernel<6><<<NNODES, 192, 0, stream>>>(P, a3s, a3d, ssrc, sdst);
  aggregate_kernel<6, 1><<<NNODES, 128, 0, stream>>>(row_ptr, srt, ssrc, sdst, P, b3, nullptr,
                                                     nullptr, x, Q);
  // mean pool per graph
  pool_kernel<<<NB, DIM, 0, stream>>>(Q, batch, flag, out);
}

// Round 2
// 876.235 us; speedup vs baseline: 1.7250x; 1.7250x over previous
//
#include <hip/hip_runtime.h>

#define NNODES 50000
#define NEDGES 500000
#define DIM    384
#define NB     64
#define SLOPE  0.2f
#define LN_EPS 1e-5f
#define EPRIME (NEDGES + NNODES)
#define POOLS  16

typedef __attribute__((ext_vector_type(8))) short short8;
typedef __attribute__((ext_vector_type(4))) float floatx4;

// ---------- helpers ----------
__device__ __forceinline__ unsigned f2ord(float f) {
  unsigned u = __float_as_uint(f);
  return (u & 0x80000000u) ? ~u : (u | 0x80000000u);
}
__device__ __forceinline__ float ord2f(unsigned k) {
  return (k & 0x80000000u) ? __uint_as_float(k & 0x7fffffffu) : __uint_as_float(~k);
}
__device__ __forceinline__ int load_i(const void* p, long long i, int is64) {
  return is64 ? (int)((const long long*)p)[i] : ((const int*)p)[i];
}
// f32 -> bf16 round-to-nearest-even (manual, header-version-proof)
__device__ __forceinline__ unsigned short f2bf(float f) {
  unsigned u = __float_as_uint(f);
  u += 0x7fffu + ((u >> 16) & 1u);
  return (unsigned short)(u >> 16);
}

// ---------- dtype detect (int64 vs int32) ----------
__global__ void detect_kernel(const int* __restrict__ ei32, int* __restrict__ flag) {
  __shared__ int nz;
  if (threadIdx.x == 0) nz = 0;
  __syncthreads();
  if (ei32[2 * threadIdx.x + 1] != 0) atomicAdd(&nz, 1);
  __syncthreads();
  if (threadIdx.x == 0) *flag = (nz == 0) ? 1 : 0;
}

// ---------- CSR build ----------
__global__ void count_kernel(const void* __restrict__ ei, const int* __restrict__ flag,
                             int* __restrict__ deg) {
  int is64 = *flag;
  for (int i = blockIdx.x * blockDim.x + threadIdx.x; i < EPRIME; i += gridDim.x * blockDim.x) {
    int d = (i < NEDGES) ? load_i(ei, (long long)NEDGES + i, is64) : (i - NEDGES);
    atomicAdd(&deg[d], 1);
  }
}

__global__ void scan_kernel(const int* __restrict__ deg, int* __restrict__ row_ptr,
                            int* __restrict__ cursor) {
  __shared__ int buf[1024];
  __shared__ int carry;
  int t = threadIdx.x;
  if (t == 0) carry = 0;
  __syncthreads();
  for (int base = 0; base < NNODES; base += 1024) {
    int idx = base + t;
    int v = (idx < NNODES) ? deg[idx] : 0;
    buf[t] = v;
    __syncthreads();
    for (int off = 1; off < 1024; off <<= 1) {
      int x = (t >= off) ? buf[t - off] : 0;
      __syncthreads();
      buf[t] += x;
      __syncthreads();
    }
    int excl = carry + buf[t] - v;
    if (idx < NNODES) { row_ptr[idx] = excl; cursor[idx] = excl; }
    __syncthreads();
    if (t == 0) carry += buf[1023];
    __syncthreads();
  }
  if (t == 0) row_ptr[NNODES] = carry;
}

__global__ void scatter_kernel(const void* __restrict__ ei, const int* __restrict__ flag,
                               int* __restrict__ cursor, int* __restrict__ srt) {
  int is64 = *flag;
  for (int i = blockIdx.x * blockDim.x + threadIdx.x; i < EPRIME; i += gridDim.x * blockDim.x) {
    int s, d;
    if (i < NEDGES) { s = load_i(ei, i, is64); d = load_i(ei, (long long)NEDGES + i, is64); }
    else            { s = d = i - NEDGES; }
    int pos = atomicAdd(&cursor[d], 1);
    srt[pos] = s;
  }
}

// ---------- conversions ----------
__global__ void convert_x_kernel(const float* __restrict__ x, unsigned short* __restrict__ xb) {
  int i = blockIdx.x * blockDim.x + threadIdx.x;   // over NNODES*DIM/4
  float4 v = ((const float4*)x)[i];
  ushort4 o;
  o.x = f2bf(v.x); o.y = f2bf(v.y); o.z = f2bf(v.z); o.w = f2bf(v.w);
  ((ushort4*)xb)[i] = o;
}

// Wt[layer][n][k] = bf16(W[layer][k][n])  (transpose so B-frag K is contiguous)
__global__ void convert_w_kernel(const float* __restrict__ W1, const float* __restrict__ W2,
                                 const float* __restrict__ W3, unsigned short* __restrict__ Wt) {
  const float* W = (blockIdx.y == 0) ? W1 : (blockIdx.y == 1) ? W2 : W3;
  unsigned short* o = Wt + (size_t)blockIdx.y * DIM * DIM;
  int n = blockIdx.x;
  int k = threadIdx.x;
  o[n * DIM + k] = f2bf(W[k * DIM + n]);
}

// ---------- bf16 MFMA GEMM: C[M,384](f32) = A[M,384](bf16) @ Bt[384,384](bf16, N-major) ----------
// m97 structure: 128x128 tile, BK=32, 4 waves each owning 64x64 (4x4 MFMA tiles),
// global_load_lds width=16 staging (wave-uniform base + lane*16 — unpadded LDS).
__global__ __launch_bounds__(256)
void gemm_bf16_kernel(const unsigned short* __restrict__ A,
                      const unsigned short* __restrict__ Bt,
                      float* __restrict__ C, int M) {
  __shared__ unsigned short As[128 * 32];
  __shared__ unsigned short Bs[128 * 32];
  int tid = threadIdx.x;
  int lane = tid & 63;
  int wave = tid >> 6;
  int bm = blockIdx.x * 128;
  int bn = blockIdx.y * 128;
  int wm = (wave & 1) * 64;
  int wn = (wave >> 1) * 64;
  int l16 = lane & 15;
  int lq  = lane >> 4;

  floatx4 acc[4][4];
#pragma unroll
  for (int mi = 0; mi < 4; ++mi)
#pragma unroll
    for (int ni = 0; ni < 4; ++ni)
      acc[mi][ni] = (floatx4){0.f, 0.f, 0.f, 0.f};

  for (int k0 = 0; k0 < DIM; k0 += 32) {
    __syncthreads();
#pragma unroll
    for (int i = 0; i < 2; ++i) {
      int c = i * 256 + tid;          // chunk id: LDS dst = c*16B = uniform base + lane*16 ✓
      int r = c >> 2;                 // 4 chunks (64B) per 32-elem row
      int col = (c & 3) << 3;
      int ra = bm + r; if (ra >= M) ra = M - 1;   // clamp; OOB rows never stored
      __builtin_amdgcn_global_load_lds(
          (const __attribute__((address_space(1))) void*)(A + (size_t)ra * DIM + k0 + col),
          (__attribute__((address_space(3))) void*)(As + c * 8), 16, 0, 0);
      __builtin_amdgcn_global_load_lds(
          (const __attribute__((address_space(1))) void*)(Bt + (size_t)(bn + r) * DIM + k0 + col),
          (__attribute__((address_space(3))) void*)(Bs + c * 8), 16, 0, 0);
    }
    __syncthreads();
    short8 av[4], bv[4];
#pragma unroll
    for (int mi = 0; mi < 4; ++mi)
      av[mi] = *(const short8*)&As[(wm + mi * 16 + l16) * 32 + lq * 8];
#pragma unroll
    for (int ni = 0; ni < 4; ++ni)
      bv[ni] = *(const short8*)&Bs[(wn + ni * 16 + l16) * 32 + lq * 8];
#pragma unroll
    for (int mi = 0; mi < 4; ++mi)
#pragma unroll
      for (int ni = 0; ni < 4; ++ni)
        acc[mi][ni] = __builtin_amdgcn_mfma_f32_16x16x32_bf16(av[mi], bv[ni], acc[mi][ni], 0, 0, 0);
  }

  // C/D layout: col = lane&15, row = (lane>>4)*4 + reg  [m89/m91-verified]
#pragma unroll
  for (int mi = 0; mi < 4; ++mi) {
#pragma unroll
    for (int r = 0; r < 4; ++r) {
      int row = bm + wm + mi * 16 + lq * 4 + r;
      if (row < M) {
#pragma unroll
        for (int ni = 0; ni < 4; ++ni)
          C[(size_t)row * DIM + bn + wn + ni * 16 + l16] = acc[mi][ni][r];
      }
    }
  }
}

// ---------- attention scores ----------
template <int H>
__global__ void score_kernel(const float* __restrict__ hmat,
                             const float* __restrict__ asrc, const float* __restrict__ adst,
                             float* __restrict__ ssrc, float* __restrict__ sdst) {
  constexpr int C = DIM / H;
  constexpr int PER = C / 32;
  int n = blockIdx.x;
  int t = threadIdx.x;               // H*32 threads
  int hh = t >> 5, lane = t & 31;
  const float* row = hmat + (size_t)n * DIM + hh * C;
  const float* as = asrc + hh * C;
  const float* ad = adst + hh * C;
  float s1 = 0.f, s2 = 0.f;
#pragma unroll
  for (int i = 0; i < PER; ++i) {
    float v = row[i * 32 + lane];
    s1 += v * as[i * 32 + lane];
    s2 += v * ad[i * 32 + lane];
  }
#pragma unroll
  for (int off = 16; off > 0; off >>= 1) {
    s1 += __shfl_down(s1, off, 32);
    s2 += __shfl_down(s2, off, 32);
  }
  if (lane == 0) { ssrc[n * H + hh] = s1; sdst[n * H + hh] = s2; }
}

// ---------- per-dst softmax + aggregation + fused epilogue ----------
// MODE 0: outb = bf16(relu(LN(agg+bias)*g+be))   (next GEMM input)
// MODE 1: outf = relu(agg+bias) + xres           (pool input, f32)
template <int H, int MODE>
__global__ __launch_bounds__(128)
void aggregate_kernel(const int* __restrict__ row_ptr, const int* __restrict__ srt,
                      const float* __restrict__ ssrc, const float* __restrict__ sdst,
                      const float* __restrict__ hmat, const float* __restrict__ bias,
                      const float* __restrict__ gamma, const float* __restrict__ beta,
                      const float* __restrict__ xres, float* __restrict__ outf,
                      unsigned short* __restrict__ outb) {
  constexpr int C = DIM / H;
  constexpr int CH = 32;
  int n = blockIdx.x;
  int t = threadIdx.x;
  int start = row_ptr[n];
  int deg = row_ptr[n + 1] - start;

  __shared__ unsigned smax[H];
  __shared__ float sden[H], sdn[H], maxv[H], invd[H];
  __shared__ int lsrc[CH];
  __shared__ float lalpha[CH * H];
  __shared__ float red[256];

  if (t < H) { smax[t] = 0u; sden[t] = 0.f; sdn[t] = sdst[n * H + t]; }
  __syncthreads();
  for (int i = t; i < deg * H; i += 128) {
    int e = i / H, hh = i - e * H;
    int s = srt[start + e];
    float v = ssrc[s * H + hh] + sdn[hh];
    v = (v > 0.f) ? v : SLOPE * v;
    atomicMax(&smax[hh], f2ord(v));
  }
  __syncthreads();
  if (t < H) maxv[t] = ord2f(smax[t]);
  __syncthreads();
  for (int i = t; i < deg * H; i += 128) {
    int e = i / H, hh = i - e * H;
    int s = srt[start + e];
    float v = ssrc[s * H + hh] + sdn[hh];
    v = (v > 0.f) ? v : SLOPE * v;
    atomicAdd(&sden[hh], __expf(v - maxv[hh]));
  }
  __syncthreads();
  if (t < H) invd[t] = 1.f / (sden[t] + 1e-16f);
  __syncthreads();

  int j0 = t, j1 = t + 128, j2 = t + 256;
  int h0 = j0 / C, h1 = j1 / C, h2 = j2 / C;
  float a0 = 0.f, a1 = 0.f, a2 = 0.f;
  for (int base = 0; base < deg; base += CH) {
    int cnt = min(CH, deg - base);
    for (int i = t; i < cnt * H; i += 128) {
      int e = i / H, hh = i - e * H;
      int s = srt[start + base + e];
      if (hh == 0) lsrc[e] = s;
      float v = ssrc[s * H + hh] + sdn[hh];
      v = (v > 0.f) ? v : SLOPE * v;
      lalpha[e * H + hh] = __expf(v - maxv[hh]) * invd[hh];
    }
    __syncthreads();
    for (int e = 0; e < cnt; ++e) {
      const float* hr = hmat + (size_t)lsrc[e] * DIM;
      a0 = fmaf(lalpha[e * H + h0], hr[j0], a0);
      a1 = fmaf(lalpha[e * H + h1], hr[j1], a1);
      a2 = fmaf(lalpha[e * H + h2], hr[j2], a2);
    }
    __syncthreads();
  }
  float v0 = a0 + bias[j0], v1 = a1 + bias[j1], v2 = a2 + bias[j2];
  if (MODE == 0) {
    red[t] = v0 + v1 + v2;
    red[t + 128] = v0 * v0 + v1 * v1 + v2 * v2;
    __syncthreads();
    for (int off = 64; off > 0; off >>= 1) {
      if (t < off) { red[t] += red[t + off]; red[t + 128] += red[t + 128 + off]; }
      __syncthreads();
    }
    float mu = red[0] * (1.f / DIM);
    float var = red[128] * (1.f / DIM) - mu * mu;
    float rs = rsqrtf(var + LN_EPS);
    float y0 = (v0 - mu) * rs * gamma[j0] + beta[j0];
    float y1 = (v1 - mu) * rs * gamma[j1] + beta[j1];
    float y2 = (v2 - mu) * rs * gamma[j2] + beta[j2];
    size_t o = (size_t)n * DIM;
    outb[o + j0] = f2bf(fmaxf(y0, 0.f));
    outb[o + j1] = f2bf(fmaxf(y1, 0.f));
    outb[o + j2] = f2bf(fmaxf(y2, 0.f));
  } else {
    size_t o = (size_t)n * DIM;
    outf[o + j0] = fmaxf(v0, 0.f) + xres[o + j0];
    outf[o + j1] = fmaxf(v1, 0.f) + xres[o + j1];
    outf[o + j2] = fmaxf(v2, 0.f) + xres[o + j2];
  }
}

// ---------- global mean pool: (graph, chunk) grid, atomic partial sums ----------
__global__ void pool_kernel(const float* __restrict__ xr, const void* __restrict__ batch,
                            const int* __restrict__ flag, float* __restrict__ out) {
  int b = blockIdx.x;
  int s = blockIdx.y;
  int t = threadIdx.x;
  int is64 = *flag;
  int lo, hi;
  { int l = 0, r = NNODES;
    while (l < r) { int m = (l + r) >> 1; if (load_i(batch, m, is64) < b) l = m + 1; else r = m; }
    lo = l; }
  { int l = lo, r = NNODES;
    while (l < r) { int m = (l + r) >> 1; if (load_i(batch, m, is64) < b + 1) l = m + 1; else r = m; }
    hi = l; }
  int cnt = hi - lo;
  float inv = 1.f / (float)max(cnt, 1);
  int chunk = (cnt + POOLS - 1) / POOLS;
  int r0 = lo + s * chunk;
  int r1 = min(r0 + chunk, hi);
  float acc = 0.f;
  for (int nn = r0; nn < r1; ++nn) acc += xr[(size_t)nn * DIM + t];
  if (r1 > r0) atomicAdd(&out[b * DIM + t], acc * inv);
}

// ---------- launch ----------
extern "C" void kernel_launch(void* const* d_in, const int* in_sizes, int n_in,
                              void* d_out, int out_size, void* d_ws, size_t ws_size,
                              hipStream_t stream) {
  const float* x    = (const float*)d_in[0];
  const void*  ei   = d_in[1];
  const void*  batch= d_in[2];
  const float* W1   = (const float*)d_in[3];
  const float* a1s  = (const float*)d_in[4];
  const float* a1d  = (const float*)d_in[5];
  const float* b1   = (const float*)d_in[6];
  const float* g1   = (const float*)d_in[7];
  const float* be1  = (const float*)d_in[8];
  const float* W2   = (const float*)d_in[9];
  const float* a2s  = (const float*)d_in[10];
  const float* a2d  = (const float*)d_in[11];
  const float* b2   = (const float*)d_in[12];
  const float* g2   = (const float*)d_in[13];
  const float* be2  = (const float*)d_in[14];
  const float* W3   = (const float*)d_in[15];
  const float* a3s  = (const float*)d_in[16];
  const float* a3d  = (const float*)d_in[17];
  const float* b3   = (const float*)d_in[18];
  float* out = (float*)d_out;

  char* ws = (char*)d_ws;
  size_t off = 0;
  auto alloc = [&](size_t bytes) -> void* {
    void* p = ws + off;
    off = (off + bytes + 255) & ~(size_t)255;
    return p;
  };
  int*   flag    = (int*)alloc(4);
  // union region R (76.8 MB): Xb=[0:38.4M) bf16, Qb=[38.4M:76.8M) bf16, Qf=whole as f32.
  // Lifetimes: Xb dead after gemm1; Qb dead after gemm3; Qf written by agg3 only.
  char*  R       = (char*)alloc((size_t)NNODES * DIM * 4);
  unsigned short* Xb = (unsigned short*)R;
  unsigned short* Qb = (unsigned short*)(R + (size_t)NNODES * DIM * 2);
  float* Qf      = (float*)R;
  float* P       = (float*)alloc((size_t)NNODES * DIM * 4);
  unsigned short* Wt = (unsigned short*)alloc((size_t)3 * DIM * DIM * 2);
  float* ssrc    = (float*)alloc((size_t)NNODES * 6 * 4);
  float* sdst    = (float*)alloc((size_t)NNODES * 6 * 4);
  int*   row_ptr = (int*)alloc((size_t)(NNODES + 1) * 4);
  int*   cursor  = (int*)alloc((size_t)NNODES * 4);
  int*   deg     = (int*)alloc((size_t)NNODES * 4);
  int*   srt     = (int*)alloc((size_t)EPRIME * 4);

  detect_kernel<<<1, 256, 0, stream>>>((const int*)ei, flag);
  hipMemsetAsync(deg, 0, (size_t)NNODES * 4, stream);
  hipMemsetAsync(d_out, 0, (size_t)out_size * 4, stream);
  int eblocks = (EPRIME + 255) / 256;
  count_kernel<<<eblocks, 256, 0, stream>>>(ei, flag, deg);
  scan_kernel<<<1, 1024, 0, stream>>>(deg, row_ptr, cursor);
  scatter_kernel<<<eblocks, 256, 0, stream>>>(ei, flag, cursor, srt);

  convert_x_kernel<<<(NNODES * DIM / 4 + 255) / 256, 256, 0, stream>>>(x, Xb);
  convert_w_kernel<<<dim3(DIM, 3), DIM, 0, stream>>>(W1, W2, W3, Wt);

  dim3 ggrid((NNODES + 127) / 128, DIM / 128);

  // layer 1
  gemm_bf16_kernel<<<ggrid, 256, 0, stream>>>(Xb, Wt, P, NNODES);
  score_kernel<4><<<NNODES, 128, 0, stream>>>(P, a1s, a1d, ssrc, sdst);
  aggregate_kernel<4, 0><<<NNODES, 128, 0, stream>>>(row_ptr, srt, ssrc, sdst, P, b1, g1, be1,
                                                     nullptr, nullptr, Qb);
  // layer 2
  gemm_bf16_kernel<<<ggrid, 256, 0, stream>>>(Qb, Wt + (size_t)DIM * DIM, P, NNODES);
  score_kernel<4><<<NNODES, 128, 0, stream>>>(P, a2s, a2d, ssrc, sdst);
  aggregate_kernel<4, 0><<<NNODES, 128, 0, stream>>>(row_ptr, srt, ssrc, sdst, P, b2, g2, be2,
                                                     nullptr, nullptr, Qb);
  // layer 3 (residual fused)
  gemm_bf16_kernel<<<ggrid, 256, 0, stream>>>(Qb, Wt + (size_t)2 * DIM * DIM, P, NNODES);
  score_kernel<6><<<NNODES, 192, 0, stream>>>(P, a3s, a3d, ssrc, sdst);
  aggregate_kernel<6, 1><<<NNODES, 128, 0, stream>>>(row_ptr, srt, ssrc, sdst, P, b3, nullptr,
                                                     nullptr, x, Qf, nullptr);
  // mean pool
  pool_kernel<<<dim3(NB, POOLS), DIM, 0, stream>>>(Qf, batch, flag, out);
}

// Round 3
// 739.403 us; speedup vs baseline: 2.0442x; 1.1851x over previous
//
#include <hip/hip_runtime.h>

#define NNODES 50000
#define NEDGES 500000
#define DIM    384
#define NB     64
#define SLOPE  0.2f
#define LN_EPS 1e-5f
#define EPRIME (NEDGES + NNODES)
#define POOLS  16
#define MAXE   256   // fast-path cap on cached edges per dst (random graph: max deg ~35)

typedef __attribute__((ext_vector_type(8))) short short8;
typedef __attribute__((ext_vector_type(4))) float floatx4;

// ---------- helpers ----------
__device__ __forceinline__ unsigned f2ord(float f) {
  unsigned u = __float_as_uint(f);
  return (u & 0x80000000u) ? ~u : (u | 0x80000000u);
}
__device__ __forceinline__ float ord2f(unsigned k) {
  return (k & 0x80000000u) ? __uint_as_float(k & 0x7fffffffu) : __uint_as_float(~k);
}
__device__ __forceinline__ int load_i(const void* p, long long i, int is64) {
  return is64 ? (int)((const long long*)p)[i] : ((const int*)p)[i];
}
// f32 -> bf16 round-to-nearest-even
__device__ __forceinline__ unsigned short f2bf(float f) {
  unsigned u = __float_as_uint(f);
  u += 0x7fffu + ((u >> 16) & 1u);
  return (unsigned short)(u >> 16);
}
__device__ __forceinline__ float bf2f(unsigned short u) {
  return __uint_as_float(((unsigned)u) << 16);
}

// ---------- dtype detect (int64 vs int32) ----------
__global__ void detect_kernel(const int* __restrict__ ei32, int* __restrict__ flag) {
  __shared__ int nz;
  if (threadIdx.x == 0) nz = 0;
  __syncthreads();
  if (ei32[2 * threadIdx.x + 1] != 0) atomicAdd(&nz, 1);
  __syncthreads();
  if (threadIdx.x == 0) *flag = (nz == 0) ? 1 : 0;
}

// ---------- CSR build ----------
__global__ void count_kernel(const void* __restrict__ ei, const int* __restrict__ flag,
                             int* __restrict__ deg) {
  int is64 = *flag;
  for (int i = blockIdx.x * blockDim.x + threadIdx.x; i < EPRIME; i += gridDim.x * blockDim.x) {
    int d = (i < NEDGES) ? load_i(ei, (long long)NEDGES + i, is64) : (i - NEDGES);
    atomicAdd(&deg[d], 1);
  }
}

__global__ void scan_kernel(const int* __restrict__ deg, int* __restrict__ row_ptr,
                            int* __restrict__ cursor) {
  __shared__ int buf[1024];
  __shared__ int carry;
  int t = threadIdx.x;
  if (t == 0) carry = 0;
  __syncthreads();
  for (int base = 0; base < NNODES; base += 1024) {
    int idx = base + t;
    int v = (idx < NNODES) ? deg[idx] : 0;
    buf[t] = v;
    __syncthreads();
    for (int off = 1; off < 1024; off <<= 1) {
      int x = (t >= off) ? buf[t - off] : 0;
      __syncthreads();
      buf[t] += x;
      __syncthreads();
    }
    int excl = carry + buf[t] - v;
    if (idx < NNODES) { row_ptr[idx] = excl; cursor[idx] = excl; }
    __syncthreads();
    if (t == 0) carry += buf[1023];
    __syncthreads();
  }
  if (t == 0) row_ptr[NNODES] = carry;
}

__global__ void scatter_kernel(const void* __restrict__ ei, const int* __restrict__ flag,
                               int* __restrict__ cursor, int* __restrict__ srt) {
  int is64 = *flag;
  for (int i = blockIdx.x * blockDim.x + threadIdx.x; i < EPRIME; i += gridDim.x * blockDim.x) {
    int s, d;
    if (i < NEDGES) { s = load_i(ei, i, is64); d = load_i(ei, (long long)NEDGES + i, is64); }
    else            { s = d = i - NEDGES; }
    int pos = atomicAdd(&cursor[d], 1);
    srt[pos] = s;
  }
}

// ---------- conversions ----------
__global__ void convert_x_kernel(const float* __restrict__ x, unsigned short* __restrict__ xb) {
  int i = blockIdx.x * blockDim.x + threadIdx.x;   // over NNODES*DIM/4
  float4 v = ((const float4*)x)[i];
  ushort4 o;
  o.x = f2bf(v.x); o.y = f2bf(v.y); o.z = f2bf(v.z); o.w = f2bf(v.w);
  ((ushort4*)xb)[i] = o;
}

// Wt[layer][n][k] = bf16(W[layer][k][n])
__global__ void convert_w_kernel(const float* __restrict__ W1, const float* __restrict__ W2,
                                 const float* __restrict__ W3, unsigned short* __restrict__ Wt) {
  const float* W = (blockIdx.y == 0) ? W1 : (blockIdx.y == 1) ? W2 : W3;
  unsigned short* o = Wt + (size_t)blockIdx.y * DIM * DIM;
  int n = blockIdx.x;
  int k = threadIdx.x;
  o[n * DIM + k] = f2bf(W[k * DIM + n]);
}

// ---------- bf16 MFMA GEMM: Cb[M,384](bf16) = A[M,384](bf16) @ Bt[384,384](bf16 N-major) ----------
__global__ __launch_bounds__(256)
void gemm_bf16_kernel(const unsigned short* __restrict__ A,
                      const unsigned short* __restrict__ Bt,
                      unsigned short* __restrict__ Cb, int M) {
  __shared__ unsigned short As[128 * 32];
  __shared__ unsigned short Bs[128 * 32];
  int tid = threadIdx.x;
  int lane = tid & 63;
  int wave = tid >> 6;
  int bm = blockIdx.x * 128;
  int bn = blockIdx.y * 128;
  int wm = (wave & 1) * 64;
  int wn = (wave >> 1) * 64;
  int l16 = lane & 15;
  int lq  = lane >> 4;

  floatx4 acc[4][4];
#pragma unroll
  for (int mi = 0; mi < 4; ++mi)
#pragma unroll
    for (int ni = 0; ni < 4; ++ni)
      acc[mi][ni] = (floatx4){0.f, 0.f, 0.f, 0.f};

  for (int k0 = 0; k0 < DIM; k0 += 32) {
    __syncthreads();
#pragma unroll
    for (int i = 0; i < 2; ++i) {
      int c = i * 256 + tid;
      int r = c >> 2;
      int col = (c & 3) << 3;
      int ra = bm + r; if (ra >= M) ra = M - 1;
      __builtin_amdgcn_global_load_lds(
          (const __attribute__((address_space(1))) void*)(A + (size_t)ra * DIM + k0 + col),
          (__attribute__((address_space(3))) void*)(As + c * 8), 16, 0, 0);
      __builtin_amdgcn_global_load_lds(
          (const __attribute__((address_space(1))) void*)(Bt + (size_t)(bn + r) * DIM + k0 + col),
          (__attribute__((address_space(3))) void*)(Bs + c * 8), 16, 0, 0);
    }
    __syncthreads();
    short8 av[4], bv[4];
#pragma unroll
    for (int mi = 0; mi < 4; ++mi)
      av[mi] = *(const short8*)&As[(wm + mi * 16 + l16) * 32 + lq * 8];
#pragma unroll
    for (int ni = 0; ni < 4; ++ni)
      bv[ni] = *(const short8*)&Bs[(wn + ni * 16 + l16) * 32 + lq * 8];
#pragma unroll
    for (int mi = 0; mi < 4; ++mi)
#pragma unroll
      for (int ni = 0; ni < 4; ++ni)
        acc[mi][ni] = __builtin_amdgcn_mfma_f32_16x16x32_bf16(av[mi], bv[ni], acc[mi][ni], 0, 0, 0);
  }

  // C/D layout: col = lane&15, row = (lane>>4)*4 + reg
#pragma unroll
  for (int mi = 0; mi < 4; ++mi) {
#pragma unroll
    for (int r = 0; r < 4; ++r) {
      int row = bm + wm + mi * 16 + lq * 4 + r;
      if (row < M) {
#pragma unroll
        for (int ni = 0; ni < 4; ++ni)
          Cb[(size_t)row * DIM + bn + wn + ni * 16 + l16] = f2bf(acc[mi][ni][r]);
      }
    }
  }
}

// ---------- attention scores (bf16 h) ----------
template <int H>
__global__ void score_kernel(const unsigned short* __restrict__ hmat,
                             const float* __restrict__ asrc, const float* __restrict__ adst,
                             float* __restrict__ ssrc, float* __restrict__ sdst) {
  constexpr int C = DIM / H;
  constexpr int PER = C / 32;
  int n = blockIdx.x;
  int t = threadIdx.x;               // H*32 threads
  int hh = t >> 5, lane = t & 31;
  const unsigned short* row = hmat + (size_t)n * DIM + hh * C;
  const float* as = asrc + hh * C;
  const float* ad = adst + hh * C;
  float s1 = 0.f, s2 = 0.f;
#pragma unroll
  for (int i = 0; i < PER; ++i) {
    float v = bf2f(row[i * 32 + lane]);
    s1 += v * as[i * 32 + lane];
    s2 += v * ad[i * 32 + lane];
  }
#pragma unroll
  for (int off = 16; off > 0; off >>= 1) {
    s1 += __shfl_down(s1, off, 32);
    s2 += __shfl_down(s2, off, 32);
  }
  if (lane == 0) { ssrc[n * H + hh] = s1; sdst[n * H + hh] = s2; }
}

// ---------- per-dst softmax + aggregation + fused epilogue (bf16 h) ----------
// MODE 0: outb = bf16(relu(LN(agg+bias)*g+be))   MODE 1: outf = relu(agg+bias) + xres
template <int H, int MODE>
__global__ __launch_bounds__(128)
void aggregate_kernel(const int* __restrict__ row_ptr, const int* __restrict__ srt,
                      const float* __restrict__ ssrc, const float* __restrict__ sdst,
                      const unsigned short* __restrict__ hmat, const float* __restrict__ bias,
                      const float* __restrict__ gamma, const float* __restrict__ beta,
                      const float* __restrict__ xres, float* __restrict__ outf,
                      unsigned short* __restrict__ outb) {
  constexpr int C = DIM / H;
  int n = blockIdx.x;
  int t = threadIdx.x;
  int start = row_ptr[n];
  int deg = row_ptr[n + 1] - start;

  __shared__ float sdn[H];
  __shared__ float lalpha[MAXE * H];
  __shared__ int lsrc[MAXE];
  __shared__ unsigned smax[H];
  __shared__ float sden[H], maxv[H], invd[H];
  __shared__ float red[256];

  if (t < H) { sdn[t] = sdst[n * H + t]; smax[t] = 0u; sden[t] = 0.f; }
  __syncthreads();

  int j0 = t, j1 = t + 128, j2 = t + 256;
  int h0 = j0 / C, h1 = j1 / C, h2 = j2 / C;
  float a0 = 0.f, a1 = 0.f, a2 = 0.f;

  if (deg <= MAXE) {
    // fast path: cache leaky scores once, per-head serial softmax (deg ~ 11)
    for (int i = t; i < deg * H; i += 128) {
      int e = i / H, hh = i - e * H;
      int s = srt[start + e];
      if (hh == 0) lsrc[e] = s;
      float v = ssrc[s * H + hh] + sdn[hh];
      lalpha[i] = (v > 0.f) ? v : SLOPE * v;
    }
    __syncthreads();
    if (t < H) {
      float m = -1e30f;
      for (int e = 0; e < deg; ++e) m = fmaxf(m, lalpha[e * H + t]);
      float d = 0.f;
      for (int e = 0; e < deg; ++e) d += __expf(lalpha[e * H + t] - m);
      float inv = 1.f / (d + 1e-16f);
      for (int e = 0; e < deg; ++e) lalpha[e * H + t] = __expf(lalpha[e * H + t] - m) * inv;
    }
    __syncthreads();
    for (int e = 0; e < deg; ++e) {
      const unsigned short* hr = hmat + (size_t)lsrc[e] * DIM;
      a0 = fmaf(lalpha[e * H + h0], bf2f(hr[j0]), a0);
      a1 = fmaf(lalpha[e * H + h1], bf2f(hr[j1]), a1);
      a2 = fmaf(lalpha[e * H + h2], bf2f(hr[j2]), a2);
    }
  } else {
    // fallback: 3-pass chunked (correctness guard for pathological degree)
    for (int i = t; i < deg * H; i += 128) {
      int e = i / H, hh = i - e * H;
      int s = srt[start + e];
      float v = ssrc[s * H + hh] + sdn[hh];
      v = (v > 0.f) ? v : SLOPE * v;
      atomicMax(&smax[hh], f2ord(v));
    }
    __syncthreads();
    if (t < H) maxv[t] = ord2f(smax[t]);
    __syncthreads();
    for (int i = t; i < deg * H; i += 128) {
      int e = i / H, hh = i - e * H;
      int s = srt[start + e];
      float v = ssrc[s * H + hh] + sdn[hh];
      v = (v > 0.f) ? v : SLOPE * v;
      atomicAdd(&sden[hh], __expf(v - maxv[hh]));
    }
    __syncthreads();
    if (t < H) invd[t] = 1.f / (sden[t] + 1e-16f);
    __syncthreads();
    for (int base = 0; base < deg; base += MAXE) {
      int cnt = min(MAXE, deg - base);
      for (int i = t; i < cnt * H; i += 128) {
        int e = i / H, hh = i - e * H;
        int s = srt[start + base + e];
        if (hh == 0) lsrc[e] = s;
        float v = ssrc[s * H + hh] + sdn[hh];
        v = (v > 0.f) ? v : SLOPE * v;
        lalpha[e * H + hh] = __expf(v - maxv[hh]) * invd[hh];
      }
      __syncthreads();
      for (int e = 0; e < cnt; ++e) {
        const unsigned short* hr = hmat + (size_t)lsrc[e] * DIM;
        a0 = fmaf(lalpha[e * H + h0], bf2f(hr[j0]), a0);
        a1 = fmaf(lalpha[e * H + h1], bf2f(hr[j1]), a1);
        a2 = fmaf(lalpha[e * H + h2], bf2f(hr[j2]), a2);
      }
      __syncthreads();
    }
  }

  float v0 = a0 + bias[j0], v1 = a1 + bias[j1], v2 = a2 + bias[j2];
  if (MODE == 0) {
    red[t] = v0 + v1 + v2;
    red[t + 128] = v0 * v0 + v1 * v1 + v2 * v2;
    __syncthreads();
    for (int off = 64; off > 0; off >>= 1) {
      if (t < off) { red[t] += red[t + off]; red[t + 128] += red[t + 128 + off]; }
      __syncthreads();
    }
    float mu = red[0] * (1.f / DIM);
    float var = red[128] * (1.f / DIM) - mu * mu;
    float rs = rsqrtf(var + LN_EPS);
    float y0 = (v0 - mu) * rs * gamma[j0] + beta[j0];
    float y1 = (v1 - mu) * rs * gamma[j1] + beta[j1];
    float y2 = (v2 - mu) * rs * gamma[j2] + beta[j2];
    size_t o = (size_t)n * DIM;
    outb[o + j0] = f2bf(fmaxf(y0, 0.f));
    outb[o + j1] = f2bf(fmaxf(y1, 0.f));
    outb[o + j2] = f2bf(fmaxf(y2, 0.f));
  } else {
    size_t o = (size_t)n * DIM;
    outf[o + j0] = fmaxf(v0, 0.f) + xres[o + j0];
    outf[o + j1] = fmaxf(v1, 0.f) + xres[o + j1];
    outf[o + j2] = fmaxf(v2, 0.f) + xres[o + j2];
  }
}

// ---------- global mean pool ----------
__global__ void pool_kernel(const float* __restrict__ xr, const void* __restrict__ batch,
                            const int* __restrict__ flag, float* __restrict__ out) {
  int b = blockIdx.x;
  int s = blockIdx.y;
  int t = threadIdx.x;
  int is64 = *flag;
  int lo, hi;
  { int l = 0, r = NNODES;
    while (l < r) { int m = (l + r) >> 1; if (load_i(batch, m, is64) < b) l = m + 1; else r = m; }
    lo = l; }
  { int l = lo, r = NNODES;
    while (l < r) { int m = (l + r) >> 1; if (load_i(batch, m, is64) < b + 1) l = m + 1; else r = m; }
    hi = l; }
  int cnt = hi - lo;
  float inv = 1.f / (float)max(cnt, 1);
  int chunk = (cnt + POOLS - 1) / POOLS;
  int r0 = lo + s * chunk;
  int r1 = min(r0 + chunk, hi);
  float acc = 0.f;
  for (int nn = r0; nn < r1; ++nn) acc += xr[(size_t)nn * DIM + t];
  if (r1 > r0) atomicAdd(&out[b * DIM + t], acc * inv);
}

// ---------- launch ----------
extern "C" void kernel_launch(void* const* d_in, const int* in_sizes, int n_in,
                              void* d_out, int out_size, void* d_ws, size_t ws_size,
                              hipStream_t stream) {
  const float* x    = (const float*)d_in[0];
  const void*  ei   = d_in[1];
  const void*  batch= d_in[2];
  const float* W1   = (const float*)d_in[3];
  const float* a1s  = (const float*)d_in[4];
  const float* a1d  = (const float*)d_in[5];
  const float* b1   = (const float*)d_in[6];
  const float* g1   = (const float*)d_in[7];
  const float* be1  = (const float*)d_in[8];
  const float* W2   = (const float*)d_in[9];
  const float* a2s  = (const float*)d_in[10];
  const float* a2d  = (const float*)d_in[11];
  const float* b2   = (const float*)d_in[12];
  const float* g2   = (const float*)d_in[13];
  const float* be2  = (const float*)d_in[14];
  const float* W3   = (const float*)d_in[15];
  const float* a3s  = (const float*)d_in[16];
  const float* a3d  = (const float*)d_in[17];
  const float* b3   = (const float*)d_in[18];
  float* out = (float*)d_out;

  char* ws = (char*)d_ws;
  size_t off = 0;
  auto alloc = [&](size_t bytes) -> void* {
    void* p = ws + off;
    off = (off + bytes + 255) & ~(size_t)255;
    return p;
  };
  int*   flag    = (int*)alloc(4);
  // union region R (76.8 MB): Xb=[0:38.4M) bf16, Qb=[38.4:76.8) bf16, Qf=whole as f32.
  char*  R       = (char*)alloc((size_t)NNODES * DIM * 4);
  unsigned short* Xb = (unsigned short*)R;
  unsigned short* Qb = (unsigned short*)(R + (size_t)NNODES * DIM * 2);
  float* Qf      = (float*)R;
  unsigned short* P = (unsigned short*)alloc((size_t)NNODES * DIM * 2);  // h (bf16)
  unsigned short* Wt = (unsigned short*)alloc((size_t)3 * DIM * DIM * 2);
  float* ssrc    = (float*)alloc((size_t)NNODES * 6 * 4);
  float* sdst    = (float*)alloc((size_t)NNODES * 6 * 4);
  int*   row_ptr = (int*)alloc((size_t)(NNODES + 1) * 4);
  int*   cursor  = (int*)alloc((size_t)NNODES * 4);
  int*   deg     = (int*)alloc((size_t)NNODES * 4);
  int*   srt     = (int*)alloc((size_t)EPRIME * 4);

  detect_kernel<<<1, 256, 0, stream>>>((const int*)ei, flag);
  hipMemsetAsync(deg, 0, (size_t)NNODES * 4, stream);
  hipMemsetAsync(d_out, 0, (size_t)out_size * 4, stream);
  int eblocks = (EPRIME + 255) / 256;
  count_kernel<<<eblocks, 256, 0, stream>>>(ei, flag, deg);
  scan_kernel<<<1, 1024, 0, stream>>>(deg, row_ptr, cursor);
  scatter_kernel<<<eblocks, 256, 0, stream>>>(ei, flag, cursor, srt);

  convert_x_kernel<<<(NNODES * DIM / 4 + 255) / 256, 256, 0, stream>>>(x, Xb);
  convert_w_kernel<<<dim3(DIM, 3), DIM, 0, stream>>>(W1, W2, W3, Wt);

  dim3 ggrid((NNODES + 127) / 128, DIM / 128);

  // layer 1
  gemm_bf16_kernel<<<ggrid, 256, 0, stream>>>(Xb, Wt, P, NNODES);
  score_kernel<4><<<NNODES, 128, 0, stream>>>(P, a1s, a1d, ssrc, sdst);
  aggregate_kernel<4, 0><<<NNODES, 128, 0, stream>>>(row_ptr, srt, ssrc, sdst, P, b1, g1, be1,
                                                     nullptr, nullptr, Qb);
  // layer 2
  gemm_bf16_kernel<<<ggrid, 256, 0, stream>>>(Qb, Wt + (size_t)DIM * DIM, P, NNODES);
  score_kernel<4><<<NNODES, 128, 0, stream>>>(P, a2s, a2d, ssrc, sdst);
  aggregate_kernel<4, 0><<<NNODES, 128, 0, stream>>>(row_ptr, srt, ssrc, sdst, P, b2, g2, be2,
                                                     nullptr, nullptr, Qb);
  // layer 3 (residual fused)
  gemm_bf16_kernel<<<ggrid, 256, 0, stream>>>(Qb, Wt + (size_t)2 * DIM * DIM, P, NNODES);
  score_kernel<6><<<NNODES, 192, 0, stream>>>(P, a3s, a3d, ssrc, sdst);
  aggregate_kernel<6, 1><<<NNODES, 128, 0, stream>>>(row_ptr, srt, ssrc, sdst, P, b3, nullptr,
                                                     nullptr, x, Qf, nullptr);
  // mean pool
  pool_kernel<<<dim3(NB, POOLS), DIM, 0, stream>>>(Qf, batch, flag, out);
}

// Round 4
// 712.208 us; speedup vs baseline: 2.1222x; 1.0382x over previous
//
#include <hip/hip_runtime.h>

#define NNODES 50000
#define NEDGES 500000
#define DIM    384
#define NB     64
#define SLOPE  0.2f
#define LN_EPS 1e-5f
#define EPRIME (NEDGES + NNODES)
#define POOLS  16

typedef __attribute__((ext_vector_type(8))) short short8;
typedef __attribute__((ext_vector_type(4))) float floatx4;

// ---------- helpers ----------
__device__ __forceinline__ int load_i(const void* p, long long i, int is64) {
  return is64 ? (int)((const long long*)p)[i] : ((const int*)p)[i];
}
// f32 -> bf16 round-to-nearest-even
__device__ __forceinline__ unsigned short f2bf(float f) {
  unsigned u = __float_as_uint(f);
  u += 0x7fffu + ((u >> 16) & 1u);
  return (unsigned short)(u >> 16);
}
__device__ __forceinline__ float bf2f(unsigned short u) {
  return __uint_as_float(((unsigned)u) << 16);
}

// ---------- dtype detect (int64 vs int32) ----------
__global__ void detect_kernel(const int* __restrict__ ei32, int* __restrict__ flag) {
  __shared__ int nz;
  if (threadIdx.x == 0) nz = 0;
  __syncthreads();
  if (ei32[2 * threadIdx.x + 1] != 0) atomicAdd(&nz, 1);
  __syncthreads();
  if (threadIdx.x == 0) *flag = (nz == 0) ? 1 : 0;
}

// ---------- CSR build ----------
__global__ void count_kernel(const void* __restrict__ ei, const int* __restrict__ flag,
                             int* __restrict__ deg) {
  int is64 = *flag;
  for (int i = blockIdx.x * blockDim.x + threadIdx.x; i < EPRIME; i += gridDim.x * blockDim.x) {
    int d = (i < NEDGES) ? load_i(ei, (long long)NEDGES + i, is64) : (i - NEDGES);
    atomicAdd(&deg[d], 1);
  }
}

__global__ void scan_kernel(const int* __restrict__ deg, int* __restrict__ row_ptr,
                            int* __restrict__ cursor) {
  __shared__ int buf[1024];
  __shared__ int carry;
  int t = threadIdx.x;
  if (t == 0) carry = 0;
  __syncthreads();
  for (int base = 0; base < NNODES; base += 1024) {
    int idx = base + t;
    int v = (idx < NNODES) ? deg[idx] : 0;
    buf[t] = v;
    __syncthreads();
    for (int off = 1; off < 1024; off <<= 1) {
      int x = (t >= off) ? buf[t - off] : 0;
      __syncthreads();
      buf[t] += x;
      __syncthreads();
    }
    int excl = carry + buf[t] - v;
    if (idx < NNODES) { row_ptr[idx] = excl; cursor[idx] = excl; }
    __syncthreads();
    if (t == 0) carry += buf[1023];
    __syncthreads();
  }
  if (t == 0) row_ptr[NNODES] = carry;
}

__global__ void scatter_kernel(const void* __restrict__ ei, const int* __restrict__ flag,
                               int* __restrict__ cursor, int* __restrict__ srt) {
  int is64 = *flag;
  for (int i = blockIdx.x * blockDim.x + threadIdx.x; i < EPRIME; i += gridDim.x * blockDim.x) {
    int s, d;
    if (i < NEDGES) { s = load_i(ei, i, is64); d = load_i(ei, (long long)NEDGES + i, is64); }
    else            { s = d = i - NEDGES; }
    int pos = atomicAdd(&cursor[d], 1);
    srt[pos] = s;
  }
}

// ---------- conversions ----------
__global__ void convert_x_kernel(const float* __restrict__ x, unsigned short* __restrict__ xb) {
  int i = blockIdx.x * blockDim.x + threadIdx.x;   // over NNODES*DIM/4
  float4 v = ((const float4*)x)[i];
  ushort4 o;
  o.x = f2bf(v.x); o.y = f2bf(v.y); o.z = f2bf(v.z); o.w = f2bf(v.w);
  ((ushort4*)xb)[i] = o;
}

// Wt[layer][n][k] = bf16(W[layer][k][n])
__global__ void convert_w_kernel(const float* __restrict__ W1, const float* __restrict__ W2,
                                 const float* __restrict__ W3, unsigned short* __restrict__ Wt) {
  const float* W = (blockIdx.y == 0) ? W1 : (blockIdx.y == 1) ? W2 : W3;
  unsigned short* o = Wt + (size_t)blockIdx.y * DIM * DIM;
  int n = blockIdx.x;
  int k = threadIdx.x;
  o[n * DIM + k] = f2bf(W[k * DIM + n]);
}

// ---------- bf16 MFMA GEMM: Cb[M,384](bf16) = A[M,384](bf16) @ Bt[384,384](bf16 N-major) ----------
__global__ __launch_bounds__(256)
void gemm_bf16_kernel(const unsigned short* __restrict__ A,
                      const unsigned short* __restrict__ Bt,
                      unsigned short* __restrict__ Cb, int M) {
  __shared__ unsigned short As[128 * 32];
  __shared__ unsigned short Bs[128 * 32];
  int tid = threadIdx.x;
  int lane = tid & 63;
  int wave = tid >> 6;
  int bm = blockIdx.x * 128;
  int bn = blockIdx.y * 128;
  int wm = (wave & 1) * 64;
  int wn = (wave >> 1) * 64;
  int l16 = lane & 15;
  int lq  = lane >> 4;

  floatx4 acc[4][4];
#pragma unroll
  for (int mi = 0; mi < 4; ++mi)
#pragma unroll
    for (int ni = 0; ni < 4; ++ni)
      acc[mi][ni] = (floatx4){0.f, 0.f, 0.f, 0.f};

  for (int k0 = 0; k0 < DIM; k0 += 32) {
    __syncthreads();
#pragma unroll
    for (int i = 0; i < 2; ++i) {
      int c = i * 256 + tid;
      int r = c >> 2;
      int col = (c & 3) << 3;
      int ra = bm + r; if (ra >= M) ra = M - 1;
      __builtin_amdgcn_global_load_lds(
          (const __attribute__((address_space(1))) void*)(A + (size_t)ra * DIM + k0 + col),
          (__attribute__((address_space(3))) void*)(As + c * 8), 16, 0, 0);
      __builtin_amdgcn_global_load_lds(
          (const __attribute__((address_space(1))) void*)(Bt + (size_t)(bn + r) * DIM + k0 + col),
          (__attribute__((address_space(3))) void*)(Bs + c * 8), 16, 0, 0);
    }
    __syncthreads();
    short8 av[4], bv[4];
#pragma unroll
    for (int mi = 0; mi < 4; ++mi)
      av[mi] = *(const short8*)&As[(wm + mi * 16 + l16) * 32 + lq * 8];
#pragma unroll
    for (int ni = 0; ni < 4; ++ni)
      bv[ni] = *(const short8*)&Bs[(wn + ni * 16 + l16) * 32 + lq * 8];
#pragma unroll
    for (int mi = 0; mi < 4; ++mi)
#pragma unroll
      for (int ni = 0; ni < 4; ++ni)
        acc[mi][ni] = __builtin_amdgcn_mfma_f32_16x16x32_bf16(av[mi], bv[ni], acc[mi][ni], 0, 0, 0);
  }

  // C/D layout: col = lane&15, row = (lane>>4)*4 + reg
#pragma unroll
  for (int mi = 0; mi < 4; ++mi) {
#pragma unroll
    for (int r = 0; r < 4; ++r) {
      int row = bm + wm + mi * 16 + lq * 4 + r;
      if (row < M) {
#pragma unroll
        for (int ni = 0; ni < 4; ++ni)
          Cb[(size_t)row * DIM + bn + wn + ni * 16 + l16] = f2bf(acc[mi][ni][r]);
      }
    }
  }
}

// ---------- attention scores (bf16 h) ----------
template <int H>
__global__ void score_kernel(const unsigned short* __restrict__ hmat,
                             const float* __restrict__ asrc, const float* __restrict__ adst,
                             float* __restrict__ ssrc, float* __restrict__ sdst) {
  constexpr int C = DIM / H;
  constexpr int PER = C / 32;
  int n = blockIdx.x;
  int t = threadIdx.x;               // H*32 threads
  int hh = t >> 5, lane = t & 31;
  const unsigned short* row = hmat + (size_t)n * DIM + hh * C;
  const float* as = asrc + hh * C;
  const float* ad = adst + hh * C;
  float s1 = 0.f, s2 = 0.f;
#pragma unroll
  for (int i = 0; i < PER; ++i) {
    float v = bf2f(row[i * 32 + lane]);
    s1 += v * as[i * 32 + lane];
    s2 += v * ad[i * 32 + lane];
  }
#pragma unroll
  for (int off = 16; off > 0; off >>= 1) {
    s1 += __shfl_down(s1, off, 32);
    s2 += __shfl_down(s2, off, 32);
  }
  if (lane == 0) { ssrc[n * H + hh] = s1; sdst[n * H + hh] = s2; }
}

// ---------- wave-per-node softmax + aggregation + fused epilogue (bf16 h) ----------
// One wave per dst node; lanes 0..47 own 8 contiguous columns (head-uniform: C%8==0).
// Online softmax (chunk=64 edges) in registers; gather via dwordx4 with scalar row base.
// MODE 0: outb = bf16(relu(LN(agg+bias)*g+be))   MODE 1: outf = relu(agg+bias) + xres
template <int H, int MODE>
__global__ __launch_bounds__(256)
void aggregate_kernel(const int* __restrict__ row_ptr, const int* __restrict__ srt,
                      const float* __restrict__ ssrc, const float* __restrict__ sdst,
                      const unsigned short* __restrict__ hmat, const float* __restrict__ bias,
                      const float* __restrict__ gamma, const float* __restrict__ beta,
                      const float* __restrict__ xres, float* __restrict__ outf,
                      unsigned short* __restrict__ outb) {
  constexpr int C = DIM / H;
  int wave = threadIdx.x >> 6;
  int lane = threadIdx.x & 63;
  int n = blockIdx.x * 4 + wave;
  int start = row_ptr[n];
  int deg = row_ptr[n + 1] - start;

  __shared__ float wexp_all[4][H][68];   // [wave][head][edge], pad 68 breaks bank aliasing
  float (*wexp)[68] = wexp_all[wave];

  bool colane = lane < 48;
  int lc = min(lane, 47);            // lanes 48-63 shadow lane 47 (same cache line, no extra BW)
  int j = lc * 8;                    // my first column
  int myhead = j / C;                // head-uniform across my 8 cols (C % 8 == 0)

  float sdn[H];
#pragma unroll
  for (int h = 0; h < H; ++h) sdn[h] = sdst[n * H + h];

  float M[H], S[H];
#pragma unroll
  for (int h = 0; h < H; ++h) { M[h] = -1e30f; S[h] = 0.f; }
  float acc[8];
#pragma unroll
  for (int i = 0; i < 8; ++i) acc[i] = 0.f;

  for (int base = 0; base < deg; base += 64) {
    int cnt = min(64, deg - base);
    int s = 0;
    float sc[H];
    if (lane < cnt) {
      s = srt[start + base + lane];
#pragma unroll
      for (int h = 0; h < H; ++h) {
        float v = ssrc[s * H + h] + sdn[h];
        sc[h] = fmaxf(v, SLOPE * v);     // leaky_relu
      }
    } else {
#pragma unroll
      for (int h = 0; h < H; ++h) sc[h] = -1e30f;
    }
    // chunk max (butterfly over 64 lanes)
    float cm[H];
#pragma unroll
    for (int h = 0; h < H; ++h) cm[h] = sc[h];
#pragma unroll
    for (int off = 32; off > 0; off >>= 1)
#pragma unroll
      for (int h = 0; h < H; ++h) cm[h] = fmaxf(cm[h], __shfl_xor(cm[h], off));
    // online-softmax update
    float r[H], ex[H];
#pragma unroll
    for (int h = 0; h < H; ++h) {
      float Mn = fmaxf(M[h], cm[h]);
      r[h] = __expf(M[h] - Mn);          // first chunk: exp(-huge)=0, S/acc are 0 anyway
      M[h] = Mn;
      ex[h] = __expf(sc[h] - Mn);        // padding lanes -> 0
      wexp[h][lane] = ex[h];
    }
    asm volatile("s_waitcnt lgkmcnt(0)" ::: "memory");
    __builtin_amdgcn_wave_barrier();
#pragma unroll
    for (int h = 0; h < H; ++h) {
      float cs = ex[h];
#pragma unroll
      for (int off = 32; off > 0; off >>= 1) cs += __shfl_xor(cs, off);
      S[h] = S[h] * r[h] + cs;
    }
    {
      float rr = r[myhead];
#pragma unroll
      for (int i = 0; i < 8; ++i) acc[i] *= rr;
    }
    // gather-accumulate this chunk
    for (int ee = 0; ee < cnt; ++ee) {
      int sb = __shfl(s, ee);                          // broadcast src of edge ee
      int su = __builtin_amdgcn_readfirstlane(sb);     // scalar base -> saddr loads
      float w = wexp[myhead][ee];
      const unsigned short* hr = hmat + (size_t)su * DIM + j;
      uint4 pk = *(const uint4*)hr;                    // 8 bf16 cols, 16B
      float f0 = __uint_as_float(pk.x << 16), f1 = __uint_as_float(pk.x & 0xffff0000u);
      float f2 = __uint_as_float(pk.y << 16), f3 = __uint_as_float(pk.y & 0xffff0000u);
      float f4 = __uint_as_float(pk.z << 16), f5 = __uint_as_float(pk.z & 0xffff0000u);
      float f6 = __uint_as_float(pk.w << 16), f7 = __uint_as_float(pk.w & 0xffff0000u);
      acc[0] = fmaf(w, f0, acc[0]); acc[1] = fmaf(w, f1, acc[1]);
      acc[2] = fmaf(w, f2, acc[2]); acc[3] = fmaf(w, f3, acc[3]);
      acc[4] = fmaf(w, f4, acc[4]); acc[5] = fmaf(w, f5, acc[5]);
      acc[6] = fmaf(w, f6, acc[6]); acc[7] = fmaf(w, f7, acc[7]);
    }
    __builtin_amdgcn_wave_barrier();
  }

  // epilogue
  float inv = 1.f / (S[myhead] + 1e-16f);
  float v[8];
  float4 b0 = *(const float4*)(bias + j);
  float4 b1 = *(const float4*)(bias + j + 4);
  v[0] = acc[0] * inv + b0.x; v[1] = acc[1] * inv + b0.y;
  v[2] = acc[2] * inv + b0.z; v[3] = acc[3] * inv + b0.w;
  v[4] = acc[4] * inv + b1.x; v[5] = acc[5] * inv + b1.y;
  v[6] = acc[6] * inv + b1.z; v[7] = acc[7] * inv + b1.w;

  if (MODE == 0) {
    float s1 = 0.f, s2 = 0.f;
    if (colane) {
#pragma unroll
      for (int i = 0; i < 8; ++i) { s1 += v[i]; s2 += v[i] * v[i]; }
    }
#pragma unroll
    for (int off = 32; off > 0; off >>= 1) {
      s1 += __shfl_xor(s1, off);
      s2 += __shfl_xor(s2, off);
    }
    float mu = s1 * (1.f / DIM);
    float var = s2 * (1.f / DIM) - mu * mu;
    float rs = rsqrtf(var + LN_EPS);
    if (colane) {
      float4 g0 = *(const float4*)(gamma + j);
      float4 g1 = *(const float4*)(gamma + j + 4);
      float4 e0 = *(const float4*)(beta + j);
      float4 e1 = *(const float4*)(beta + j + 4);
      float gg[8] = {g0.x, g0.y, g0.z, g0.w, g1.x, g1.y, g1.z, g1.w};
      float bb[8] = {e0.x, e0.y, e0.z, e0.w, e1.x, e1.y, e1.z, e1.w};
      ushort4 o0, o1;
      unsigned short oy[8];
#pragma unroll
      for (int i = 0; i < 8; ++i) {
        float y = (v[i] - mu) * rs * gg[i] + bb[i];
        oy[i] = f2bf(fmaxf(y, 0.f));
      }
      o0.x = oy[0]; o0.y = oy[1]; o0.z = oy[2]; o0.w = oy[3];
      o1.x = oy[4]; o1.y = oy[5]; o1.z = oy[6]; o1.w = oy[7];
      *(ushort4*)(outb + (size_t)n * DIM + j) = o0;
      *(ushort4*)(outb + (size_t)n * DIM + j + 4) = o1;
    }
  } else {
    if (colane) {
      const float* xr = xres + (size_t)n * DIM + j;
      float4 x0 = *(const float4*)xr;
      float4 x1 = *(const float4*)(xr + 4);
      float4 o0, o1;
      o0.x = fmaxf(v[0], 0.f) + x0.x; o0.y = fmaxf(v[1], 0.f) + x0.y;
      o0.z = fmaxf(v[2], 0.f) + x0.z; o0.w = fmaxf(v[3], 0.f) + x0.w;
      o1.x = fmaxf(v[4], 0.f) + x1.x; o1.y = fmaxf(v[5], 0.f) + x1.y;
      o1.z = fmaxf(v[6], 0.f) + x1.z; o1.w = fmaxf(v[7], 0.f) + x1.w;
      float* op = outf + (size_t)n * DIM + j;
      *(float4*)op = o0;
      *(float4*)(op + 4) = o1;
    }
  }
}

// ---------- global mean pool ----------
__global__ void pool_kernel(const float* __restrict__ xr, const void* __restrict__ batch,
                            const int* __restrict__ flag, float* __restrict__ out) {
  int b = blockIdx.x;
  int s = blockIdx.y;
  int t = threadIdx.x;
  int is64 = *flag;
  int lo, hi;
  { int l = 0, r = NNODES;
    while (l < r) { int m = (l + r) >> 1; if (load_i(batch, m, is64) < b) l = m + 1; else r = m; }
    lo = l; }
  { int l = lo, r = NNODES;
    while (l < r) { int m = (l + r) >> 1; if (load_i(batch, m, is64) < b + 1) l = m + 1; else r = m; }
    hi = l; }
  int cnt = hi - lo;
  float inv = 1.f / (float)max(cnt, 1);
  int chunk = (cnt + POOLS - 1) / POOLS;
  int r0 = lo + s * chunk;
  int r1 = min(r0 + chunk, hi);
  float acc = 0.f;
  for (int nn = r0; nn < r1; ++nn) acc += xr[(size_t)nn * DIM + t];
  if (r1 > r0) atomicAdd(&out[b * DIM + t], acc * inv);
}

// ---------- launch ----------
extern "C" void kernel_launch(void* const* d_in, const int* in_sizes, int n_in,
                              void* d_out, int out_size, void* d_ws, size_t ws_size,
                              hipStream_t stream) {
  const float* x    = (const float*)d_in[0];
  const void*  ei   = d_in[1];
  const void*  batch= d_in[2];
  const float* W1   = (const float*)d_in[3];
  const float* a1s  = (const float*)d_in[4];
  const float* a1d  = (const float*)d_in[5];
  const float* b1   = (const float*)d_in[6];
  const float* g1   = (const float*)d_in[7];
  const float* be1  = (const float*)d_in[8];
  const float* W2   = (const float*)d_in[9];
  const float* a2s  = (const float*)d_in[10];
  const float* a2d  = (const float*)d_in[11];
  const float* b2   = (const float*)d_in[12];
  const float* g2   = (const float*)d_in[13];
  const float* be2  = (const float*)d_in[14];
  const float* W3   = (const float*)d_in[15];
  const float* a3s  = (const float*)d_in[16];
  const float* a3d  = (const float*)d_in[17];
  const float* b3   = (const float*)d_in[18];
  float* out = (float*)d_out;

  char* ws = (char*)d_ws;
  size_t off = 0;
  auto alloc = [&](size_t bytes) -> void* {
    void* p = ws + off;
    off = (off + bytes + 255) & ~(size_t)255;
    return p;
  };
  int*   flag    = (int*)alloc(4);
  // union region R (76.8 MB): Xb=[0:38.4M) bf16, Qb=[38.4:76.8) bf16, Qf=whole as f32.
  char*  R       = (char*)alloc((size_t)NNODES * DIM * 4);
  unsigned short* Xb = (unsigned short*)R;
  unsigned short* Qb = (unsigned short*)(R + (size_t)NNODES * DIM * 2);
  float* Qf      = (float*)R;
  unsigned short* P = (unsigned short*)alloc((size_t)NNODES * DIM * 2);  // h (bf16)
  unsigned short* Wt = (unsigned short*)alloc((size_t)3 * DIM * DIM * 2);
  float* ssrc    = (float*)alloc((size_t)NNODES * 6 * 4);
  float* sdst    = (float*)alloc((size_t)NNODES * 6 * 4);
  int*   row_ptr = (int*)alloc((size_t)(NNODES + 1) * 4);
  int*   cursor  = (int*)alloc((size_t)NNODES * 4);
  int*   deg     = (int*)alloc((size_t)NNODES * 4);
  int*   srt     = (int*)alloc((size_t)EPRIME * 4);

  detect_kernel<<<1, 256, 0, stream>>>((const int*)ei, flag);
  hipMemsetAsync(deg, 0, (size_t)NNODES * 4, stream);
  hipMemsetAsync(d_out, 0, (size_t)out_size * 4, stream);
  int eblocks = (EPRIME + 255) / 256;
  count_kernel<<<eblocks, 256, 0, stream>>>(ei, flag, deg);
  scan_kernel<<<1, 1024, 0, stream>>>(deg, row_ptr, cursor);
  scatter_kernel<<<eblocks, 256, 0, stream>>>(ei, flag, cursor, srt);

  convert_x_kernel<<<(NNODES * DIM / 4 + 255) / 256, 256, 0, stream>>>(x, Xb);
  convert_w_kernel<<<dim3(DIM, 3), DIM, 0, stream>>>(W1, W2, W3, Wt);

  dim3 ggrid((NNODES + 127) / 128, DIM / 128);
  int agrid = NNODES / 4;   // 12500 blocks x 4 waves (exact)

  // layer 1
  gemm_bf16_kernel<<<ggrid, 256, 0, stream>>>(Xb, Wt, P, NNODES);
  score_kernel<4><<<NNODES, 128, 0, stream>>>(P, a1s, a1d, ssrc, sdst);
  aggregate_kernel<4, 0><<<agrid, 256, 0, stream>>>(row_ptr, srt, ssrc, sdst, P, b1, g1, be1,
                                                    nullptr, nullptr, Qb);
  // layer 2
  gemm_bf16_kernel<<<ggrid, 256, 0, stream>>>(Qb, Wt + (size_t)DIM * DIM, P, NNODES);
  score_kernel<4><<<NNODES, 128, 0, stream>>>(P, a2s, a2d, ssrc, sdst);
  aggregate_kernel<4, 0><<<agrid, 256, 0, stream>>>(row_ptr, srt, ssrc, sdst, P, b2, g2, be2,
                                                    nullptr, nullptr, Qb);
  // layer 3 (residual fused)
  gemm_bf16_kernel<<<ggrid, 256, 0, stream>>>(Qb, Wt + (size_t)2 * DIM * DIM, P, NNODES);
  score_kernel<6><<<NNODES, 192, 0, stream>>>(P, a3s, a3d, ssrc, sdst);
  aggregate_kernel<6, 1><<<agrid, 256, 0, stream>>>(row_ptr, srt, ssrc, sdst, P, b3, nullptr,
                                                    nullptr, x, Qf, nullptr);
  // mean pool
  pool_kernel<<<dim3(NB, POOLS), DIM, 0, stream>>>(Qf, batch, flag, out);
}

// Round 5
// 592.895 us; speedup vs baseline: 2.5493x; 1.2012x over previous
//
#include <hip/hip_runtime.h>

#define NNODES 50000
#define NEDGES 500000
#define DIM    384
#define NB     64
#define SLOPE  0.2f
#define LN_EPS 1e-5f
#define EPRIME (NEDGES + NNODES)
#define POOLS  16
#define SCANB  256
#define NSCB   ((NNODES + SCANB - 1) / SCANB)   // 196

typedef __attribute__((ext_vector_type(8))) short short8;
typedef __attribute__((ext_vector_type(4))) float floatx4;
typedef __attribute__((ext_vector_type(2))) float floatx2;

// ---------- helpers ----------
__device__ __forceinline__ int load_i(const void* p, long long i, int is64) {
  return is64 ? (int)((const long long*)p)[i] : ((const int*)p)[i];
}
__device__ __forceinline__ unsigned short f2bf(float f) {
  unsigned u = __float_as_uint(f);
  u += 0x7fffu + ((u >> 16) & 1u);
  return (unsigned short)(u >> 16);
}
__device__ __forceinline__ float bf2f(unsigned short u) {
  return __uint_as_float(((unsigned)u) << 16);
}

// ---------- dtype detect (int64 vs int32) ----------
__global__ void detect_kernel(const int* __restrict__ ei32, int* __restrict__ flag) {
  __shared__ int nz;
  if (threadIdx.x == 0) nz = 0;
  __syncthreads();
  if (ei32[2 * threadIdx.x + 1] != 0) atomicAdd(&nz, 1);
  __syncthreads();
  if (threadIdx.x == 0) *flag = (nz == 0) ? 1 : 0;
}

// ---------- CSR build ----------
__global__ void count_kernel(const void* __restrict__ ei, const int* __restrict__ flag,
                             int* __restrict__ deg) {
  int is64 = *flag;
  for (int i = blockIdx.x * blockDim.x + threadIdx.x; i < EPRIME; i += gridDim.x * blockDim.x) {
    int d = (i < NEDGES) ? load_i(ei, (long long)NEDGES + i, is64) : (i - NEDGES);
    atomicAdd(&deg[d], 1);
  }
}

// 3-phase multi-block exclusive scan (replaces serial single-block scan)
__global__ void scan1_kernel(const int* __restrict__ deg, int* __restrict__ row_ptr,
                             int* __restrict__ btot) {
  __shared__ int buf[SCANB];
  int t = threadIdx.x, idx = blockIdx.x * SCANB + t;
  int v = (idx < NNODES) ? deg[idx] : 0;
  buf[t] = v;
  __syncthreads();
  for (int off = 1; off < SCANB; off <<= 1) {
    int x = (t >= off) ? buf[t - off] : 0;
    __syncthreads();
    buf[t] += x;
    __syncthreads();
  }
  if (idx < NNODES) row_ptr[idx] = buf[t] - v;        // local exclusive
  if (t == SCANB - 1) btot[blockIdx.x] = buf[t];
}
__global__ void scan2_kernel(int* __restrict__ btot) {
  __shared__ int buf[256];
  int t = threadIdx.x;
  int v = (t < NSCB) ? btot[t] : 0;
  buf[t] = v;
  __syncthreads();
  for (int off = 1; off < 256; off <<= 1) {
    int x = (t >= off) ? buf[t - off] : 0;
    __syncthreads();
    buf[t] += x;
    __syncthreads();
  }
  if (t < NSCB) btot[t] = buf[t] - v;                 // exclusive block offsets
}
__global__ void scan3_kernel(int* __restrict__ row_ptr, int* __restrict__ cursor,
                             const int* __restrict__ btot) {
  int idx = blockIdx.x * SCANB + threadIdx.x;
  if (idx < NNODES) {
    int v = row_ptr[idx] + btot[blockIdx.x];
    row_ptr[idx] = v;
    cursor[idx] = v;
  }
  if (idx == 0) row_ptr[NNODES] = EPRIME;             // total is a compile-time constant
}

__global__ void scatter_kernel(const void* __restrict__ ei, const int* __restrict__ flag,
                               int* __restrict__ cursor, int* __restrict__ srt) {
  int is64 = *flag;
  for (int i = blockIdx.x * blockDim.x + threadIdx.x; i < EPRIME; i += gridDim.x * blockDim.x) {
    int s, d;
    if (i < NEDGES) { s = load_i(ei, i, is64); d = load_i(ei, (long long)NEDGES + i, is64); }
    else            { s = d = i - NEDGES; }
    int pos = atomicAdd(&cursor[d], 1);
    srt[pos] = s;
  }
}

// ---------- conversions ----------
__global__ void convert_x_kernel(const float* __restrict__ x, unsigned short* __restrict__ xb) {
  int i = blockIdx.x * blockDim.x + threadIdx.x;   // over NNODES*DIM/4
  float4 v = ((const float4*)x)[i];
  ushort4 o;
  o.x = f2bf(v.x); o.y = f2bf(v.y); o.z = f2bf(v.z); o.w = f2bf(v.w);
  ((ushort4*)xb)[i] = o;
}

// Wt[layer][n][k] = bf16(W[layer][k][n])
__global__ void convert_w_kernel(const float* __restrict__ W1, const float* __restrict__ W2,
                                 const float* __restrict__ W3, unsigned short* __restrict__ Wt) {
  const float* W = (blockIdx.y == 0) ? W1 : (blockIdx.y == 1) ? W2 : W3;
  unsigned short* o = Wt + (size_t)blockIdx.y * DIM * DIM;
  int n = blockIdx.x;
  int k = threadIdx.x;
  o[n * DIM + k] = f2bf(W[k * DIM + n]);
}

// ---------- bf16 MFMA GEMM: Cb[M,384](bf16) = A[M,384](bf16) @ Bt[384,384](bf16 N-major) ----------
__global__ __launch_bounds__(256)
void gemm_bf16_kernel(const unsigned short* __restrict__ A,
                      const unsigned short* __restrict__ Bt,
                      unsigned short* __restrict__ Cb, int M) {
  __shared__ unsigned short As[128 * 32];
  __shared__ unsigned short Bs[128 * 32];
  int tid = threadIdx.x;
  int lane = tid & 63;
  int wave = tid >> 6;
  int bm = blockIdx.x * 128;
  int bn = blockIdx.y * 128;
  int wm = (wave & 1) * 64;
  int wn = (wave >> 1) * 64;
  int l16 = lane & 15;
  int lq  = lane >> 4;

  floatx4 acc[4][4];
#pragma unroll
  for (int mi = 0; mi < 4; ++mi)
#pragma unroll
    for (int ni = 0; ni < 4; ++ni)
      acc[mi][ni] = (floatx4){0.f, 0.f, 0.f, 0.f};

  for (int k0 = 0; k0 < DIM; k0 += 32) {
    __syncthreads();
#pragma unroll
    for (int i = 0; i < 2; ++i) {
      int c = i * 256 + tid;
      int r = c >> 2;
      int col = (c & 3) << 3;
      int ra = bm + r; if (ra >= M) ra = M - 1;
      __builtin_amdgcn_global_load_lds(
          (const __attribute__((address_space(1))) void*)(A + (size_t)ra * DIM + k0 + col),
          (__attribute__((address_space(3))) void*)(As + c * 8), 16, 0, 0);
      __builtin_amdgcn_global_load_lds(
          (const __attribute__((address_space(1))) void*)(Bt + (size_t)(bn + r) * DIM + k0 + col),
          (__attribute__((address_space(3))) void*)(Bs + c * 8), 16, 0, 0);
    }
    __syncthreads();
    short8 av[4], bv[4];
#pragma unroll
    for (int mi = 0; mi < 4; ++mi)
      av[mi] = *(const short8*)&As[(wm + mi * 16 + l16) * 32 + lq * 8];
#pragma unroll
    for (int ni = 0; ni < 4; ++ni)
      bv[ni] = *(const short8*)&Bs[(wn + ni * 16 + l16) * 32 + lq * 8];
#pragma unroll
    for (int mi = 0; mi < 4; ++mi)
#pragma unroll
      for (int ni = 0; ni < 4; ++ni)
        acc[mi][ni] = __builtin_amdgcn_mfma_f32_16x16x32_bf16(av[mi], bv[ni], acc[mi][ni], 0, 0, 0);
  }

  // C/D layout: col = lane&15, row = (lane>>4)*4 + reg
#pragma unroll
  for (int mi = 0; mi < 4; ++mi) {
#pragma unroll
    for (int r = 0; r < 4; ++r) {
      int row = bm + wm + mi * 16 + lq * 4 + r;
      if (row < M) {
#pragma unroll
        for (int ni = 0; ni < 4; ++ni)
          Cb[(size_t)row * DIM + bn + wn + ni * 16 + l16] = f2bf(acc[mi][ni][r]);
      }
    }
  }
}

// ---------- attention scores + fp8 table emit ----------
// Wave per node (4/block). Lane lc<48 owns 8 contiguous cols (head-uniform).
// Reads bf16 h, computes s_src/s_dst dots, writes fp8-e4m3 copy of h for the gather.
template <int H>
__global__ __launch_bounds__(256)
void score_kernel(const unsigned short* __restrict__ hmat,
                  const float* __restrict__ asrc, const float* __restrict__ adst,
                  float* __restrict__ ssrc, float* __restrict__ sdst,
                  unsigned char* __restrict__ h8) {
  constexpr int C = DIM / H;
  constexpr int LPH = 48 / H;          // lanes per head (12 for H=4, 8 for H=6)
  int wave = threadIdx.x >> 6, lane = threadIdx.x & 63;
  int n = blockIdx.x * 4 + wave;
  bool colane = lane < 48;
  int lc = min(lane, 47);
  int j = lc * 8;

  __shared__ float r1[4][64], r2[4][64];
  float s1 = 0.f, s2 = 0.f;
  if (colane) {
    uint4 pk = *(const uint4*)(hmat + (size_t)n * DIM + j);
    float f[8];
    f[0] = __uint_as_float(pk.x << 16); f[1] = __uint_as_float(pk.x & 0xffff0000u);
    f[2] = __uint_as_float(pk.y << 16); f[3] = __uint_as_float(pk.y & 0xffff0000u);
    f[4] = __uint_as_float(pk.z << 16); f[5] = __uint_as_float(pk.z & 0xffff0000u);
    f[6] = __uint_as_float(pk.w << 16); f[7] = __uint_as_float(pk.w & 0xffff0000u);
    float4 a0 = *(const float4*)(asrc + j);
    float4 a1 = *(const float4*)(asrc + j + 4);
    float4 d0 = *(const float4*)(adst + j);
    float4 d1 = *(const float4*)(adst + j + 4);
    s1 = f[0]*a0.x + f[1]*a0.y + f[2]*a0.z + f[3]*a0.w
       + f[4]*a1.x + f[5]*a1.y + f[6]*a1.z + f[7]*a1.w;
    s2 = f[0]*d0.x + f[1]*d0.y + f[2]*d0.z + f[3]*d0.w
       + f[4]*d1.x + f[5]*d1.y + f[6]*d1.z + f[7]*d1.w;
    // fp8 e4m3 pack (gfx950 OCP format)
    int w0 = __builtin_amdgcn_cvt_pk_fp8_f32(f[0], f[1], 0, false);
    w0 = __builtin_amdgcn_cvt_pk_fp8_f32(f[2], f[3], w0, true);
    int w1 = __builtin_amdgcn_cvt_pk_fp8_f32(f[4], f[5], 0, false);
    w1 = __builtin_amdgcn_cvt_pk_fp8_f32(f[6], f[7], w1, true);
    uint2 st; st.x = (unsigned)w0; st.y = (unsigned)w1;
    *(uint2*)(h8 + (size_t)n * DIM + j) = st;
  }
  r1[wave][lane] = colane ? s1 : 0.f;
  r2[wave][lane] = colane ? s2 : 0.f;
  asm volatile("s_waitcnt lgkmcnt(0)" ::: "memory");
  __builtin_amdgcn_wave_barrier();
  if (lane < H) {
    float a = 0.f;
#pragma unroll
    for (int k = 0; k < LPH; ++k) a += r1[wave][lane * LPH + k];
    ssrc[n * H + lane] = a;
  } else if (lane >= 8 && lane < 8 + H) {
    int h = lane - 8;
    float a = 0.f;
#pragma unroll
    for (int k = 0; k < LPH; ++k) a += r2[wave][h * LPH + k];
    sdst[n * H + h] = a;
  }
}

// ---------- wave-per-node softmax + fp8 gather aggregation + fused epilogue ----------
// MODE 0: outb = bf16(relu(LN(agg+bias)*g+be))   MODE 1: outf = relu(agg+bias) + xres
template <int H, int MODE>
__global__ __launch_bounds__(256)
void aggregate_kernel(const int* __restrict__ row_ptr, const int* __restrict__ srt,
                      const float* __restrict__ ssrc, const float* __restrict__ sdst,
                      const unsigned char* __restrict__ h8, const float* __restrict__ bias,
                      const float* __restrict__ gamma, const float* __restrict__ beta,
                      const float* __restrict__ xres, float* __restrict__ outf,
                      unsigned short* __restrict__ outb) {
  constexpr int C = DIM / H;
  int wave = threadIdx.x >> 6;
  int lane = threadIdx.x & 63;
  int n = blockIdx.x * 4 + wave;
  int start = row_ptr[n];
  int deg = row_ptr[n + 1] - start;

  __shared__ float wexp_all[4][H][68];
  float (*wexp)[68] = wexp_all[wave];

  bool colane = lane < 48;
  int lc = min(lane, 47);
  int j = lc * 8;
  int myhead = j / C;

  float sdn[H];
#pragma unroll
  for (int h = 0; h < H; ++h) sdn[h] = sdst[n * H + h];

  float M[H], S[H];
#pragma unroll
  for (int h = 0; h < H; ++h) { M[h] = -1e30f; S[h] = 0.f; }
  float acc[8];
#pragma unroll
  for (int i = 0; i < 8; ++i) acc[i] = 0.f;

  for (int base = 0; base < deg; base += 64) {
    int cnt = min(64, deg - base);
    int s = 0;
    float sc[H];
    if (lane < cnt) {
      s = srt[start + base + lane];
      if (H == 4) {
        float4 sv = *(const float4*)(ssrc + s * 4);
        float svv[4] = {sv.x, sv.y, sv.z, sv.w};
#pragma unroll
        for (int h = 0; h < 4; ++h) {
          float v = svv[h] + sdn[h];
          sc[h] = fmaxf(v, SLOPE * v);
        }
      } else {
#pragma unroll
        for (int h = 0; h < H; ++h) {
          float v = ssrc[s * H + h] + sdn[h];
          sc[h] = fmaxf(v, SLOPE * v);
        }
      }
    } else {
#pragma unroll
      for (int h = 0; h < H; ++h) sc[h] = -1e30f;
    }
    float cm[H];
#pragma unroll
    for (int h = 0; h < H; ++h) cm[h] = sc[h];
#pragma unroll
    for (int off = 32; off > 0; off >>= 1)
#pragma unroll
      for (int h = 0; h < H; ++h) cm[h] = fmaxf(cm[h], __shfl_xor(cm[h], off));
    float r[H], ex[H];
#pragma unroll
    for (int h = 0; h < H; ++h) {
      float Mn = fmaxf(M[h], cm[h]);
      r[h] = __expf(M[h] - Mn);
      M[h] = Mn;
      ex[h] = __expf(sc[h] - Mn);
      wexp[h][lane] = ex[h];
    }
    asm volatile("s_waitcnt lgkmcnt(0)" ::: "memory");
    __builtin_amdgcn_wave_barrier();
#pragma unroll
    for (int h = 0; h < H; ++h) {
      float cs = ex[h];
#pragma unroll
      for (int off = 32; off > 0; off >>= 1) cs += __shfl_xor(cs, off);
      S[h] = S[h] * r[h] + cs;
    }
    {
      float rr = r[myhead];
#pragma unroll
      for (int i = 0; i < 8; ++i) acc[i] *= rr;
    }
    // fp8 gather-accumulate (8B/lane, 384B/row)
    for (int ee = 0; ee < cnt; ++ee) {
      int sb = __shfl(s, ee);
      int su = __builtin_amdgcn_readfirstlane(sb);
      float w = wexp[myhead][ee];
      const unsigned char* hr = h8 + (size_t)su * DIM + j;
      uint2 pk = *(const uint2*)hr;
      floatx2 p0 = __builtin_amdgcn_cvt_pk_f32_fp8((int)pk.x, false);
      floatx2 p1 = __builtin_amdgcn_cvt_pk_f32_fp8((int)pk.x, true);
      floatx2 p2 = __builtin_amdgcn_cvt_pk_f32_fp8((int)pk.y, false);
      floatx2 p3 = __builtin_amdgcn_cvt_pk_f32_fp8((int)pk.y, true);
      acc[0] = fmaf(w, p0.x, acc[0]); acc[1] = fmaf(w, p0.y, acc[1]);
      acc[2] = fmaf(w, p1.x, acc[2]); acc[3] = fmaf(w, p1.y, acc[3]);
      acc[4] = fmaf(w, p2.x, acc[4]); acc[5] = fmaf(w, p2.y, acc[5]);
      acc[6] = fmaf(w, p3.x, acc[6]); acc[7] = fmaf(w, p3.y, acc[7]);
    }
    __builtin_amdgcn_wave_barrier();
  }

  // epilogue
  float inv = 1.f / (S[myhead] + 1e-16f);
  float v[8];
  float4 b0 = *(const float4*)(bias + j);
  float4 b1 = *(const float4*)(bias + j + 4);
  v[0] = acc[0] * inv + b0.x; v[1] = acc[1] * inv + b0.y;
  v[2] = acc[2] * inv + b0.z; v[3] = acc[3] * inv + b0.w;
  v[4] = acc[4] * inv + b1.x; v[5] = acc[5] * inv + b1.y;
  v[6] = acc[6] * inv + b1.z; v[7] = acc[7] * inv + b1.w;

  if (MODE == 0) {
    float s1 = 0.f, s2 = 0.f;
    if (colane) {
#pragma unroll
      for (int i = 0; i < 8; ++i) { s1 += v[i]; s2 += v[i] * v[i]; }
    }
#pragma unroll
    for (int off = 32; off > 0; off >>= 1) {
      s1 += __shfl_xor(s1, off);
      s2 += __shfl_xor(s2, off);
    }
    float mu = s1 * (1.f / DIM);
    float var = s2 * (1.f / DIM) - mu * mu;
    float rs = rsqrtf(var + LN_EPS);
    if (colane) {
      float4 g0 = *(const float4*)(gamma + j);
      float4 g1 = *(const float4*)(gamma + j + 4);
      float4 e0 = *(const float4*)(beta + j);
      float4 e1 = *(const float4*)(beta + j + 4);
      float gg[8] = {g0.x, g0.y, g0.z, g0.w, g1.x, g1.y, g1.z, g1.w};
      float bb[8] = {e0.x, e0.y, e0.z, e0.w, e1.x, e1.y, e1.z, e1.w};
      ushort4 o0, o1;
      unsigned short oy[8];
#pragma unroll
      for (int i = 0; i < 8; ++i) {
        float y = (v[i] - mu) * rs * gg[i] + bb[i];
        oy[i] = f2bf(fmaxf(y, 0.f));
      }
      o0.x = oy[0]; o0.y = oy[1]; o0.z = oy[2]; o0.w = oy[3];
      o1.x = oy[4]; o1.y = oy[5]; o1.z = oy[6]; o1.w = oy[7];
      *(ushort4*)(outb + (size_t)n * DIM + j) = o0;
      *(ushort4*)(outb + (size_t)n * DIM + j + 4) = o1;
    }
  } else {
    if (colane) {
      const float* xr = xres + (size_t)n * DIM + j;
      float4 x0 = *(const float4*)xr;
      float4 x1 = *(const float4*)(xr + 4);
      float4 o0, o1;
      o0.x = fmaxf(v[0], 0.f) + x0.x; o0.y = fmaxf(v[1], 0.f) + x0.y;
      o0.z = fmaxf(v[2], 0.f) + x0.z; o0.w = fmaxf(v[3], 0.f) + x0.w;
      o1.x = fmaxf(v[4], 0.f) + x1.x; o1.y = fmaxf(v[5], 0.f) + x1.y;
      o1.z = fmaxf(v[6], 0.f) + x1.z; o1.w = fmaxf(v[7], 0.f) + x1.w;
      float* op = outf + (size_t)n * DIM + j;
      *(float4*)op = o0;
      *(float4*)(op + 4) = o1;
    }
  }
}

// ---------- global mean pool ----------
__global__ void pool_kernel(const float* __restrict__ xr, const void* __restrict__ batch,
                            const int* __restrict__ flag, float* __restrict__ out) {
  int b = blockIdx.x;
  int s = blockIdx.y;
  int t = threadIdx.x;
  int is64 = *flag;
  int lo, hi;
  { int l = 0, r = NNODES;
    while (l < r) { int m = (l + r) >> 1; if (load_i(batch, m, is64) < b) l = m + 1; else r = m; }
    lo = l; }
  { int l = lo, r = NNODES;
    while (l < r) { int m = (l + r) >> 1; if (load_i(batch, m, is64) < b + 1) l = m + 1; else r = m; }
    hi = l; }
  int cnt = hi - lo;
  float inv = 1.f / (float)max(cnt, 1);
  int chunk = (cnt + POOLS - 1) / POOLS;
  int r0 = lo + s * chunk;
  int r1 = min(r0 + chunk, hi);
  float acc = 0.f;
  for (int nn = r0; nn < r1; ++nn) acc += xr[(size_t)nn * DIM + t];
  if (r1 > r0) atomicAdd(&out[b * DIM + t], acc * inv);
}

// ---------- launch ----------
extern "C" void kernel_launch(void* const* d_in, const int* in_sizes, int n_in,
                              void* d_out, int out_size, void* d_ws, size_t ws_size,
                              hipStream_t stream) {
  const float* x    = (const float*)d_in[0];
  const void*  ei   = d_in[1];
  const void*  batch= d_in[2];
  const float* W1   = (const float*)d_in[3];
  const float* a1s  = (const float*)d_in[4];
  const float* a1d  = (const float*)d_in[5];
  const float* b1   = (const float*)d_in[6];
  const float* g1   = (const float*)d_in[7];
  const float* be1  = (const float*)d_in[8];
  const float* W2   = (const float*)d_in[9];
  const float* a2s  = (const float*)d_in[10];
  const float* a2d  = (const float*)d_in[11];
  const float* b2   = (const float*)d_in[12];
  const float* g2   = (const float*)d_in[13];
  const float* be2  = (const float*)d_in[14];
  const float* W3   = (const float*)d_in[15];
  const float* a3s  = (const float*)d_in[16];
  const float* a3d  = (const float*)d_in[17];
  const float* b3   = (const float*)d_in[18];
  float* out = (float*)d_out;

  char* ws = (char*)d_ws;
  size_t off = 0;
  auto alloc = [&](size_t bytes) -> void* {
    void* p = ws + off;
    off = (off + bytes + 255) & ~(size_t)255;
    return p;
  };
  int*   flag    = (int*)alloc(4);
  // union region R (76.8 MB): Xb=[0:38.4M) bf16, Qb=[38.4:76.8) bf16, Qf=whole as f32.
  char*  R       = (char*)alloc((size_t)NNODES * DIM * 4);
  unsigned short* Xb = (unsigned short*)R;
  unsigned short* Qb = (unsigned short*)(R + (size_t)NNODES * DIM * 2);
  float* Qf      = (float*)R;
  unsigned short* P = (unsigned short*)alloc((size_t)NNODES * DIM * 2);  // h (bf16)
  unsigned char*  P8 = (unsigned char*)alloc((size_t)NNODES * DIM);     // h (fp8 e4m3)
  unsigned short* Wt = (unsigned short*)alloc((size_t)3 * DIM * DIM * 2);
  float* ssrc    = (float*)alloc((size_t)NNODES * 6 * 4);
  float* sdst    = (float*)alloc((size_t)NNODES * 6 * 4);
  int*   row_ptr = (int*)alloc((size_t)(NNODES + 1) * 4);
  int*   cursor  = (int*)alloc((size_t)NNODES * 4);
  int*   deg     = (int*)alloc((size_t)NNODES * 4);
  int*   btot    = (int*)alloc((size_t)NSCB * 4);
  int*   srt     = (int*)alloc((size_t)EPRIME * 4);

  detect_kernel<<<1, 256, 0, stream>>>((const int*)ei, flag);
  hipMemsetAsync(deg, 0, (size_t)NNODES * 4, stream);
  hipMemsetAsync(d_out, 0, (size_t)out_size * 4, stream);
  int eblocks = (EPRIME + 255) / 256;
  count_kernel<<<eblocks, 256, 0, stream>>>(ei, flag, deg);
  scan1_kernel<<<NSCB, SCANB, 0, stream>>>(deg, row_ptr, btot);
  scan2_kernel<<<1, 256, 0, stream>>>(btot);
  scan3_kernel<<<NSCB, SCANB, 0, stream>>>(row_ptr, cursor, btot);
  scatter_kernel<<<eblocks, 256, 0, stream>>>(ei, flag, cursor, srt);

  convert_x_kernel<<<(NNODES * DIM / 4 + 255) / 256, 256, 0, stream>>>(x, Xb);
  convert_w_kernel<<<dim3(DIM, 3), DIM, 0, stream>>>(W1, W2, W3, Wt);

  dim3 ggrid((NNODES + 127) / 128, DIM / 128);
  int agrid = NNODES / 4;   // 12500 blocks x 4 waves (exact)

  // layer 1
  gemm_bf16_kernel<<<ggrid, 256, 0, stream>>>(Xb, Wt, P, NNODES);
  score_kernel<4><<<agrid, 256, 0, stream>>>(P, a1s, a1d, ssrc, sdst, P8);
  aggregate_kernel<4, 0><<<agrid, 256, 0, stream>>>(row_ptr, srt, ssrc, sdst, P8, b1, g1, be1,
                                                    nullptr, nullptr, Qb);
  // layer 2
  gemm_bf16_kernel<<<ggrid, 256, 0, stream>>>(Qb, Wt + (size_t)DIM * DIM, P, NNODES);
  score_kernel<4><<<agrid, 256, 0, stream>>>(P, a2s, a2d, ssrc, sdst, P8);
  aggregate_kernel<4, 0><<<agrid, 256, 0, stream>>>(row_ptr, srt, ssrc, sdst, P8, b2, g2, be2,
                                                    nullptr, nullptr, Qb);
  // layer 3 (residual fused)
  gemm_bf16_kernel<<<ggrid, 256, 0, stream>>>(Qb, Wt + (size_t)2 * DIM * DIM, P, NNODES);
  score_kernel<6><<<agrid, 256, 0, stream>>>(P, a3s, a3d, ssrc, sdst, P8);
  aggregate_kernel<6, 1><<<agrid, 256, 0, stream>>>(row_ptr, srt, ssrc, sdst, P8, b3, nullptr,
                                                    nullptr, x, Qf, nullptr);
  // mean pool
  pool_kernel<<<dim3(NB, POOLS), DIM, 0, stream>>>(Qf, batch, flag, out);
}